// Round 6
// baseline (277.955 us; speedup 1.0000x reference)
//
#include <hip/hip_runtime.h>

#define HH 128
#define WW 256
#define CV_C 32
#define DISP 200

typedef __attribute__((ext_vector_type(4))) float f32x4;
typedef __attribute__((ext_vector_type(8))) short bf16x8;

__device__ inline unsigned short f2bf(float f) {
  unsigned int u = __float_as_uint(f);
  u = (u + 0x7FFFu + ((u >> 16) & 1u)) >> 16;  // RNE
  return (unsigned short)u;
}

__device__ inline float bf2f(short s) {
  return __uint_as_float(((unsigned int)(unsigned short)s) << 16);
}

// Device-scope grid barrier. Counters zeroed by hipMemsetAsync before launch.
// Spin uses atomicAdd(+0) (RMW -> coherence point; a plain load could spin on
// a stale per-XCD L2 line). threadfence = agent fence (wbL2/inv) for
// cross-XCD data visibility. Grid=256 <= co-residency capacity -> no deadlock.
__device__ inline void gbar(unsigned int* c) {
  __threadfence();
  __syncthreads();
  if (threadIdx.x == 0) {
    atomicAdd(c, 1u);
    while (atomicAdd(c, 0u) < 256u) __builtin_amdgcn_s_sleep(2);
  }
  __syncthreads();
  __threadfence();
}

// ---------------------------------------------------------------------------
// One persistent kernel, 256 blocks x 256 threads. Phases (round-4 bodies):
//   P0: weight pack (grid-strided)  +  cost-volume MFMA (2 jobs/block)
//   P1: conv1 implicit-GEMM MFMA (2 jobs/block)
//   P2: conv2 MFMA (2 jobs/block)
//   P3: conv3 MFMA (2 jobs/block)
//   P4: conv4 direct (128 px/block)
// 4 grid barriers replace 5 kernel boundaries (~7-10 us each).
// ---------------------------------------------------------------------------
__global__ __launch_bounds__(256) void mega_kernel(
    const float* __restrict__ left, const float* __restrict__ right,
    const float* __restrict__ w1, const float* __restrict__ b1,
    const float* __restrict__ g1, const float* __restrict__ be1,
    const float* __restrict__ m1, const float* __restrict__ v1,
    const float* __restrict__ w2, const float* __restrict__ b2,
    const float* __restrict__ g2, const float* __restrict__ be2,
    const float* __restrict__ m2, const float* __restrict__ v2,
    const float* __restrict__ w3, const float* __restrict__ b3,
    const float* __restrict__ g3, const float* __restrict__ be3,
    const float* __restrict__ m3, const float* __restrict__ v3,
    const float* __restrict__ w4, const float* __restrict__ b4,
    unsigned short* __restrict__ cost_t, unsigned short* __restrict__ pw1,
    unsigned short* __restrict__ pb2, unsigned short* __restrict__ pb3,
    unsigned short* __restrict__ o1t, unsigned short* __restrict__ o2t,
    unsigned short* __restrict__ o3t, float* __restrict__ out,
    unsigned int* bar) {
  __shared__ __align__(16) char smem[60672];
  const int tid = threadIdx.x;
  const int bid = blockIdx.x;
  const int lane = tid & 63;
  const int wv = tid >> 6;
  const int col = lane & 15;
  const int kg = lane >> 4;

  // ===================== P0a: weight packing (grid-strided) ================
  for (int idx = bid * 256 + tid; idx < 129024; idx += 65536) {
    // pw1[chunk 7][pos 9][kg 4][n 64][j 8]
    const int j = idx & 7;
    const int n = (idx >> 3) & 63;
    const int kgp = (idx >> 9) & 3;
    const int cp = idx >> 11;
    const int pos = cp % 9;
    const int chunk = cp / 9;
    const int ci = chunk * 32 + kgp * 8 + j;
    float v = 0.f;
    if (ci < 200) v = w1[(n * 200 + ci) * 9 + pos];
    pw1[idx] = f2bf(v);
  }
  for (int idx = bid * 256 + tid; idx < 18432; idx += 65536) {
    // pb2[pos 9][kc 2][kg 4][n 32][j 8]
    const int j = idx & 7;
    const int n = (idx >> 3) & 31;
    const int kgp = (idx >> 8) & 3;
    const int kc = (idx >> 10) & 1;
    const int pos = idx >> 11;
    const int ci = kc * 32 + kgp * 8 + j;
    pb2[idx] = f2bf(w2[(n * 64 + ci) * 9 + pos]);
  }
  for (int idx = bid * 256 + tid; idx < 4608; idx += 65536) {
    // pb3[pos 9][kg 4][n 16(8 real)][j 8]
    const int j = idx & 7;
    const int n = (idx >> 3) & 15;
    const int kgp = (idx >> 7) & 3;
    const int pos = idx >> 9;
    const int ci = kgp * 8 + j;
    float v = 0.f;
    if (n < 8) v = w3[(n * 32 + ci) * 9 + pos];
    pb3[idx] = f2bf(v);
  }

  // ===================== P0b: cost volume (2 jobs/block) ===================
  {
    unsigned short(*r_sh)[40] = (unsigned short(*)[40])smem;             // 21760
    unsigned short(*l_hi)[40] = (unsigned short(*)[40])(smem + 21760);   // 5120
    unsigned short(*l_lo)[40] = (unsigned short(*)[40])(smem + 26880);   // 5120
    unsigned short(*c_sh)[224] = (unsigned short(*)[224])(smem + 32000); // 28672
    for (int jj = 0; jj < 2; ++jj) {
      const int j = bid + jj * 256;
      const int y = j >> 2;
      const int x0 = (j & 3) * 64;
      __syncthreads();  // LDS reuse guard between jobs

      for (int c = wv; c < CV_C; c += 4) {
        const float v = left[(c * HH + y) * WW + x0 + lane];
        const unsigned short h = f2bf(v);
        l_hi[lane][c] = h;
        l_lo[lane][c] = f2bf(v - bf2f(h));
      }
      for (int c = wv; c < CV_C; c += 4) {
        for (int pq = 0; pq < 320; pq += 64) {
          const int p = pq + lane;
          if (p < 272) {
            const int xp = x0 - 208 + p;
            float v = (xp >= 0) ? right[(c * HH + y) * WW + xp] : 0.f;
            r_sh[p][c] = f2bf(v);
          }
        }
      }
      {
        bf16x8 z = {0, 0, 0, 0, 0, 0, 0, 0};
        bf16x8* cz = (bf16x8*)c_sh;
#pragma unroll
        for (int k = 0; k < 7; ++k) cz[k * 256 + tid] = z;
      }
      __syncthreads();

      const bf16x8 b_hi = *(const bf16x8*)&l_hi[16 * wv + col][kg * 8];
      const bf16x8 b_lo = *(const bf16x8*)&l_lo[16 * wv + col][kg * 8];

      for (int t = 0; t < 14; ++t) {
        const int pq = 16 * (wv - t) + 208;
        const bf16x8 a_r = *(const bf16x8*)&r_sh[pq + col][kg * 8];
        f32x4 acc = {0.f, 0.f, 0.f, 0.f};
        acc = __builtin_amdgcn_mfma_f32_16x16x32_bf16(a_r, b_hi, acc, 0, 0, 0);
        acc = __builtin_amdgcn_mfma_f32_16x16x32_bf16(a_r, b_lo, acc, 0, 0, 0);
#pragma unroll
        for (int r = 0; r < 4; ++r) {
          const int d = 200 - 16 * t + kg * 4 + r - col;
          if (d >= 0 && d < DISP) c_sh[16 * wv + col][d] = f2bf(acc[r]);
        }
      }
      __syncthreads();

#pragma unroll
      for (int k = 0; k < 7; ++k) {
        const int s = k * 256 + tid;
        const int x = s / 28;
        const int dv = s - x * 28;
        *reinterpret_cast<bf16x8*>(&cost_t[(y * WW + x0 + x) * 224 + dv * 8]) =
            *reinterpret_cast<const bf16x8*>(&c_sh[x][dv * 8]);
      }
    }
  }

  gbar(bar);

  // ===================== P1: conv1 (2 jobs/block) ==========================
  {
    unsigned short(*a_sh)[7920] = (unsigned short(*)[7920])smem;  // 2x15840 B
    const bf16x8* pwv = (const bf16x8*)pw1;
    const bf16x8 zero = {0, 0, 0, 0, 0, 0, 0, 0};
    const int m0 = (wv >> 1) * 32;
    const int n0 = (wv & 1) * 32;

    for (int jj = 0; jj < 2; ++jj) {
      const int j = bid + jj * 256;
      const int y = j >> 2;
      const int x0 = (j & 3) * 64;
      __syncthreads();

      long goff[4];
      int laddr[4];
      bool gvalid[4], lvalid[4];
#pragma unroll
      for (int it = 0; it < 4; ++it) {
        const int i = tid + it * 256;
        lvalid[it] = i < 792;  // 3*66*4
        const int row = i / 264;
        const int rem = i % 264;
        const int xx = rem >> 2;
        const int q = rem & 3;
        const int gy = y + row - 1;
        const int gx = x0 - 1 + xx;
        gvalid[it] = lvalid[it] && gy >= 0 && gy < HH && gx >= 0 && gx < WW;
        goff[it] = gvalid[it] ? (long)(gy * WW + gx) * 224 + q * 8 : 0;
        laddr[it] = (row * 66 + xx) * 40 + q * 8;
      }

      f32x4 acc[2][2];
#pragma unroll
      for (int i = 0; i < 2; ++i)
#pragma unroll
        for (int jx = 0; jx < 2; ++jx) acc[i][jx] = 0.f;

      bf16x8 stg[4];
#pragma unroll
      for (int it = 0; it < 4; ++it)
        stg[it] = gvalid[it]
                      ? *reinterpret_cast<const bf16x8*>(&cost_t[goff[it]])
                      : zero;
#pragma unroll
      for (int it = 0; it < 4; ++it)
        if (lvalid[it])
          *reinterpret_cast<bf16x8*>(&a_sh[0][laddr[it]]) = stg[it];
      __syncthreads();

      for (int chunk = 0; chunk < 7; ++chunk) {
        const int buf = chunk & 1;
        if (chunk < 6) {
#pragma unroll
          for (int it = 0; it < 4; ++it)
            stg[it] = gvalid[it] ? *reinterpret_cast<const bf16x8*>(
                                       &cost_t[goff[it] + (chunk + 1) * 32])
                                 : zero;
        }
        const bf16x8* av = (const bf16x8*)a_sh[buf];
#pragma unroll
        for (int pos = 0; pos < 9; ++pos) {
          const int ky = pos / 3;
          const int kx = pos % 3;
          const int bbase = ((chunk * 9 + pos) * 4 + kg) * 64;
          const bf16x8 b0v = pwv[bbase + n0 + col];
          const bf16x8 b1v = pwv[bbase + n0 + 16 + col];
          const bf16x8 a0v = av[(ky * 66 + m0 + col + kx) * 5 + kg];
          const bf16x8 a1v = av[(ky * 66 + m0 + 16 + col + kx) * 5 + kg];
          acc[0][0] = __builtin_amdgcn_mfma_f32_16x16x32_bf16(a0v, b0v, acc[0][0], 0, 0, 0);
          acc[0][1] = __builtin_amdgcn_mfma_f32_16x16x32_bf16(a0v, b1v, acc[0][1], 0, 0, 0);
          acc[1][0] = __builtin_amdgcn_mfma_f32_16x16x32_bf16(a1v, b0v, acc[1][0], 0, 0, 0);
          acc[1][1] = __builtin_amdgcn_mfma_f32_16x16x32_bf16(a1v, b1v, acc[1][1], 0, 0, 0);
        }
        if (chunk < 6) {
#pragma unroll
          for (int it = 0; it < 4; ++it)
            if (lvalid[it])
              *reinterpret_cast<bf16x8*>(&a_sh[buf ^ 1][laddr[it]]) = stg[it];
          __syncthreads();
        }
      }

#pragma unroll
      for (int nf = 0; nf < 2; ++nf) {
        const int c = n0 + nf * 16 + col;
        const float inv = rsqrtf(v1[c] + 1e-5f);
        const float sc = g1[c] * inv;
        const float sh = be1[c] - m1[c] * sc;
        const float bb = b1[c];
#pragma unroll
        for (int mf = 0; mf < 2; ++mf) {
#pragma unroll
          for (int rr = 0; rr < 4; ++rr) {
            const int m = m0 + mf * 16 + kg * 4 + rr;
            float vv = (acc[mf][nf][rr] + bb) * sc + sh;
            vv = fmaxf(vv, 0.f);
            o1t[((y * WW + x0 + m) << 6) + c] = f2bf(vv);
          }
        }
      }
    }
  }

  gbar(bar + 16);

  // ===================== P2: conv2 (2 jobs/block) ==========================
  {
    char* const ab = smem;  // 3*66*64 shorts = 25344 B, XOR-swizzled
    const bf16x8* pbv = (const bf16x8*)pb2;
    const int m0 = (wv >> 1) * 32;
    const int n0 = (wv & 1) * 16;

    for (int jj = 0; jj < 2; ++jj) {
      const int j = bid + jj * 256;
      const int y = j >> 2;
      const int x0 = (j & 3) * 64;
      __syncthreads();

      f32x4 acc[2];
      acc[0] = 0.f;
      acc[1] = 0.f;

      for (int i = tid; i < 1584; i += 256) {  // 3*66*8
        const int r = i >> 3;
        const int q = i & 7;
        const int rowy = r / 66;
        const int xx = r % 66;
        const int gy = y + rowy - 1;
        const int gx = x0 - 1 + xx;
        bf16x8 v = {0, 0, 0, 0, 0, 0, 0, 0};
        if (gy >= 0 && gy < HH && gx >= 0 && gx < WW)
          v = *reinterpret_cast<const bf16x8*>(
              &o1t[((gy * WW + gx) << 6) + q * 8]);
        const int byte = ((r << 7) + (q << 4)) ^ ((r & 7) << 4);
        *reinterpret_cast<bf16x8*>(ab + byte) = v;
      }
      __syncthreads();

#pragma unroll
      for (int pos = 0; pos < 9; ++pos) {
        const int ky = pos / 3;
        const int kx = pos % 3;
#pragma unroll
        for (int kc = 0; kc < 2; ++kc) {
          const bf16x8 bv = pbv[((pos * 2 + kc) * 4 + kg) * 32 + n0 + col];
#pragma unroll
          for (int mf = 0; mf < 2; ++mf) {
            const int r = ky * 66 + m0 + mf * 16 + col + kx;
            const int byte =
                ((r << 7) + (kc << 6) + (kg << 4)) ^ ((r & 7) << 4);
            const bf16x8 av = *reinterpret_cast<const bf16x8*>(ab + byte);
            acc[mf] =
                __builtin_amdgcn_mfma_f32_16x16x32_bf16(av, bv, acc[mf], 0, 0, 0);
          }
        }
      }

      const int c = n0 + col;
      const float inv = rsqrtf(v2[c] + 1e-5f);
      const float sc = g2[c] * inv;
      const float sh = be2[c] - m2[c] * sc;
      const float bb = b2[c];
#pragma unroll
      for (int mf = 0; mf < 2; ++mf) {
#pragma unroll
        for (int rr = 0; rr < 4; ++rr) {
          const int m = m0 + mf * 16 + kg * 4 + rr;
          float vv = (acc[mf][rr] + bb) * sc + sh;
          vv = fmaxf(vv, 0.f);
          o2t[((y * WW + x0 + m) << 5) + c] = f2bf(vv);
        }
      }
    }
  }

  gbar(bar + 32);

  // ===================== P3: conv3 (2 jobs/block) ==========================
  {
    char* const ab = smem;  // 3*66*32 shorts = 12672 B
    const bf16x8* pbv = (const bf16x8*)pb3;
    const int m0 = wv * 16;

    for (int jj = 0; jj < 2; ++jj) {
      const int j = bid + jj * 256;
      const int y = j >> 2;
      const int x0 = (j & 3) * 64;
      __syncthreads();

      f32x4 acc = 0.f;

      for (int i = tid; i < 792; i += 256) {  // 3*66*4
        const int r = i >> 2;
        const int q = i & 3;
        const int rowy = r / 66;
        const int xx = r % 66;
        const int gy = y + rowy - 1;
        const int gx = x0 - 1 + xx;
        bf16x8 v = {0, 0, 0, 0, 0, 0, 0, 0};
        if (gy >= 0 && gy < HH && gx >= 0 && gx < WW)
          v = *reinterpret_cast<const bf16x8*>(
              &o2t[((gy * WW + gx) << 5) + q * 8]);
        const int byte = ((r << 6) + (q << 4)) ^ ((r & 3) << 4);
        *reinterpret_cast<bf16x8*>(ab + byte) = v;
      }
      __syncthreads();

#pragma unroll
      for (int pos = 0; pos < 9; ++pos) {
        const int ky = pos / 3;
        const int kx = pos % 3;
        const bf16x8 bv = pbv[(pos * 4 + kg) * 16 + col];
        const int r = ky * 66 + m0 + col + kx;
        const int byte = ((r << 6) + (kg << 4)) ^ ((r & 3) << 4);
        const bf16x8 av = *reinterpret_cast<const bf16x8*>(ab + byte);
        acc = __builtin_amdgcn_mfma_f32_16x16x32_bf16(av, bv, acc, 0, 0, 0);
      }

      if (col < 8) {
        const int c = col;
        const float inv = rsqrtf(v3[c] + 1e-5f);
        const float sc = g3[c] * inv;
        const float sh = be3[c] - m3[c] * sc;
        const float bb = b3[c];
#pragma unroll
        for (int rr = 0; rr < 4; ++rr) {
          const int m = m0 + kg * 4 + rr;
          float vv = (acc[rr] + bb) * sc + sh;
          vv = fmaxf(vv, 0.f);
          o3t[((y * WW + x0 + m) << 3) + c] = f2bf(vv);
        }
      }
    }
  }

  gbar(bar + 48);

  // ===================== P4: conv4 (128 px/block) ==========================
  if (tid < 128) {
    const int p = bid * 128 + tid;
    const int y = p >> 8;
    const int x = p & 255;

    float wr[3][3][8];
#pragma unroll
    for (int ci = 0; ci < 8; ++ci)
#pragma unroll
      for (int ky = 0; ky < 3; ++ky)
#pragma unroll
        for (int kx = 0; kx < 3; ++kx)
          wr[ky][kx][ci] = w4[(ci * 3 + ky) * 3 + kx];

    float acc = b4[0];
#pragma unroll
    for (int ky = 0; ky < 3; ++ky) {
      const int gy = y + ky - 1;
      if (gy < 0 || gy >= HH) continue;
#pragma unroll
      for (int kx = 0; kx < 3; ++kx) {
        const int gx = x + kx - 1;
        if (gx < 0 || gx >= WW) continue;
        const bf16x8 v =
            *reinterpret_cast<const bf16x8*>(&o3t[((gy << 8) + gx) << 3]);
#pragma unroll
        for (int ci = 0; ci < 8; ++ci) acc += bf2f(v[ci]) * wr[ky][kx][ci];
      }
    }
    out[p] = acc;
  }
}

// ---------------------------------------------------------------------------
extern "C" void kernel_launch(void* const* d_in, const int* in_sizes, int n_in,
                              void* d_out, int out_size, void* d_ws,
                              size_t ws_size, hipStream_t stream) {
  const float* left = (const float*)d_in[0];
  const float* right = (const float*)d_in[1];
  const float* w1 = (const float*)d_in[2];
  const float* b1 = (const float*)d_in[3];
  const float* g1 = (const float*)d_in[4];
  const float* be1 = (const float*)d_in[5];
  const float* m1 = (const float*)d_in[6];
  const float* v1 = (const float*)d_in[7];
  const float* w2 = (const float*)d_in[8];
  const float* b2 = (const float*)d_in[9];
  const float* g2 = (const float*)d_in[10];
  const float* be2 = (const float*)d_in[11];
  const float* m2 = (const float*)d_in[12];
  const float* v2 = (const float*)d_in[13];
  const float* w3 = (const float*)d_in[14];
  const float* b3 = (const float*)d_in[15];
  const float* g3 = (const float*)d_in[16];
  const float* be3 = (const float*)d_in[17];
  const float* m3 = (const float*)d_in[18];
  const float* v3 = (const float*)d_in[19];
  const float* w4 = (const float*)d_in[20];
  const float* b4 = (const float*)d_in[21];

  // Workspace:
  //  [0, 14680064)   cost_t bf16 [128][256][224]
  //  region: +0 pw1 (262144) | +262144 pb2 (65536) | +327680 pb3 (65536)
  //          +393216  o1_t bf16 [128][256][64] (4194304)
  //          +4587520 o2_t bf16 [128][256][32] (2097152)
  //          +6684672 o3_t bf16 [128][256][8]  (524288)
  //  [33554432, +256) grid-barrier counters (zeroed per call)
  char* ws = (char*)d_ws;
  unsigned short* cost_t = (unsigned short*)ws;
  char* region = ws + 14680064;
  unsigned short* pw1 = (unsigned short*)(region + 0);
  unsigned short* pb2 = (unsigned short*)(region + 262144);
  unsigned short* pb3 = (unsigned short*)(region + 327680);
  unsigned short* o1t = (unsigned short*)(region + 393216);
  unsigned short* o2t = (unsigned short*)(region + 4587520);
  unsigned short* o3t = (unsigned short*)(region + 6684672);
  unsigned int* bar = (unsigned int*)(ws + 33554432);
  float* o4 = (float*)d_out;

  hipMemsetAsync(bar, 0, 256, stream);
  mega_kernel<<<256, 256, 0, stream>>>(
      left, right, w1, b1, g1, be1, m1, v1, w2, b2, g2, be2, m2, v2, w3, b3,
      g3, be3, m3, v3, w4, b4, cost_t, pw1, pb2, pb3, o1t, o2t, o3t, o4, bar);
}

// Round 7
// 243.203 us; speedup vs baseline: 1.1429x; 1.1429x over previous
//
#include <hip/hip_runtime.h>

#define HH 128
#define WW 256
#define CV_C 32
#define DISP 200

typedef __attribute__((ext_vector_type(4))) float f32x4;
typedef __attribute__((ext_vector_type(8))) short bf16x8;

__device__ inline unsigned short f2bf(float f) {
  unsigned int u = __float_as_uint(f);
  u = (u + 0x7FFFu + ((u >> 16) & 1u)) >> 16;  // RNE
  return (unsigned short)u;
}

__device__ inline float bf2f(short s) {
  return __uint_as_float(((unsigned int)(unsigned short)s) << 16);
}

// Grid barrier, load-spin version. Arrive: one relaxed agent-scope RMW per
// block. Wait: agent-scope LOADS (concurrent, no line ownership) + s_sleep
// backoff -- the round-6 RMW-spin serialized all probes at the coherence
// point (~60us/barrier). Fences: thread 0 only, after __syncthreads drained
// the block's stores to L2 (vmcnt0); one wbl2 covers the whole block.
__device__ inline void gbar(unsigned int* c, unsigned int tgt) {
  __syncthreads();
  if (threadIdx.x == 0) {
    __threadfence();  // wb L2 -> cross-XCD visibility of this block's stores
    __hip_atomic_fetch_add(c, 1u, __ATOMIC_RELAXED, __HIP_MEMORY_SCOPE_AGENT);
    while (__hip_atomic_load(c, __ATOMIC_RELAXED, __HIP_MEMORY_SCOPE_AGENT) <
           tgt)
      __builtin_amdgcn_s_sleep(16);
    __threadfence();  // invalidate stale L1/L2 before reading others' data
  }
  __syncthreads();
}

// ---------------------------------------------------------------------------
// One persistent kernel, 512 blocks x 256 threads (2 blocks/CU guaranteed by
// __launch_bounds__(256,2): VGPR<=256, LDS 60928*2 <= 160KB). One job/block.
//   P0: weight pack (grid-strided) + cost-volume MFMA
//   P1: conv1   P2: conv2   P3: conv3   P4: conv4
// ---------------------------------------------------------------------------
__global__ __launch_bounds__(256, 2) void mega_kernel(
    const float* __restrict__ left, const float* __restrict__ right,
    const float* __restrict__ w1, const float* __restrict__ b1,
    const float* __restrict__ g1, const float* __restrict__ be1,
    const float* __restrict__ m1, const float* __restrict__ v1,
    const float* __restrict__ w2, const float* __restrict__ b2,
    const float* __restrict__ g2, const float* __restrict__ be2,
    const float* __restrict__ m2, const float* __restrict__ v2,
    const float* __restrict__ w3, const float* __restrict__ b3,
    const float* __restrict__ g3, const float* __restrict__ be3,
    const float* __restrict__ m3, const float* __restrict__ v3,
    const float* __restrict__ w4, const float* __restrict__ b4,
    unsigned short* __restrict__ cost_t, unsigned short* __restrict__ pw1,
    unsigned short* __restrict__ pb2, unsigned short* __restrict__ pb3,
    unsigned short* __restrict__ o1t, unsigned short* __restrict__ o2t,
    unsigned short* __restrict__ o3t, float* __restrict__ out,
    unsigned int* bar) {
  __shared__ __align__(16) char smem[60672];
  const int tid = threadIdx.x;
  const int bid = blockIdx.x;
  const int lane = tid & 63;
  const int wv = tid >> 6;
  const int col = lane & 15;
  const int kg = lane >> 4;
  const int y = bid >> 2;
  const int x0 = (bid & 3) * 64;

  // ===================== P0a: weight packing (grid-strided) ================
  for (int idx = bid * 256 + tid; idx < 129024; idx += 131072) {
    // pw1[chunk 7][pos 9][kg 4][n 64][j 8]
    const int j = idx & 7;
    const int n = (idx >> 3) & 63;
    const int kgp = (idx >> 9) & 3;
    const int cp = idx >> 11;
    const int pos = cp % 9;
    const int chunk = cp / 9;
    const int ci = chunk * 32 + kgp * 8 + j;
    float v = 0.f;
    if (ci < 200) v = w1[(n * 200 + ci) * 9 + pos];
    pw1[idx] = f2bf(v);
  }
  for (int idx = bid * 256 + tid; idx < 18432; idx += 131072) {
    // pb2[pos 9][kc 2][kg 4][n 32][j 8]
    const int j = idx & 7;
    const int n = (idx >> 3) & 31;
    const int kgp = (idx >> 8) & 3;
    const int kc = (idx >> 10) & 1;
    const int pos = idx >> 11;
    const int ci = kc * 32 + kgp * 8 + j;
    pb2[idx] = f2bf(w2[(n * 64 + ci) * 9 + pos]);
  }
  for (int idx = bid * 256 + tid; idx < 4608; idx += 131072) {
    // pb3[pos 9][kg 4][n 16(8 real)][j 8]
    const int j = idx & 7;
    const int n = (idx >> 3) & 15;
    const int kgp = (idx >> 7) & 3;
    const int pos = idx >> 9;
    const int ci = kgp * 8 + j;
    float v = 0.f;
    if (n < 8) v = w3[(n * 32 + ci) * 9 + pos];
    pb3[idx] = f2bf(v);
  }

  // ===================== P0b: cost volume ==================================
  {
    unsigned short(*r_sh)[40] = (unsigned short(*)[40])smem;             // 21760
    unsigned short(*l_hi)[40] = (unsigned short(*)[40])(smem + 21760);   // 5120
    unsigned short(*l_lo)[40] = (unsigned short(*)[40])(smem + 26880);   // 5120
    unsigned short(*c_sh)[224] = (unsigned short(*)[224])(smem + 32000); // 28672

    for (int c = wv; c < CV_C; c += 4) {
      const float v = left[(c * HH + y) * WW + x0 + lane];
      const unsigned short h = f2bf(v);
      l_hi[lane][c] = h;
      l_lo[lane][c] = f2bf(v - bf2f(h));
    }
    for (int c = wv; c < CV_C; c += 4) {
      for (int pq = 0; pq < 320; pq += 64) {
        const int p = pq + lane;
        if (p < 272) {
          const int xp = x0 - 208 + p;
          float v = (xp >= 0) ? right[(c * HH + y) * WW + xp] : 0.f;
          r_sh[p][c] = f2bf(v);
        }
      }
    }
    {
      bf16x8 z = {0, 0, 0, 0, 0, 0, 0, 0};
      bf16x8* cz = (bf16x8*)c_sh;
#pragma unroll
      for (int k = 0; k < 7; ++k) cz[k * 256 + tid] = z;
    }
    __syncthreads();

    const bf16x8 b_hi = *(const bf16x8*)&l_hi[16 * wv + col][kg * 8];
    const bf16x8 b_lo = *(const bf16x8*)&l_lo[16 * wv + col][kg * 8];

    for (int t = 0; t < 14; ++t) {
      const int pq = 16 * (wv - t) + 208;
      const bf16x8 a_r = *(const bf16x8*)&r_sh[pq + col][kg * 8];
      f32x4 acc = {0.f, 0.f, 0.f, 0.f};
      acc = __builtin_amdgcn_mfma_f32_16x16x32_bf16(a_r, b_hi, acc, 0, 0, 0);
      acc = __builtin_amdgcn_mfma_f32_16x16x32_bf16(a_r, b_lo, acc, 0, 0, 0);
#pragma unroll
      for (int r = 0; r < 4; ++r) {
        const int d = 200 - 16 * t + kg * 4 + r - col;
        if (d >= 0 && d < DISP) c_sh[16 * wv + col][d] = f2bf(acc[r]);
      }
    }
    __syncthreads();

#pragma unroll
    for (int k = 0; k < 7; ++k) {
      const int s = k * 256 + tid;
      const int x = s / 28;
      const int dv = s - x * 28;
      *reinterpret_cast<bf16x8*>(&cost_t[(y * WW + x0 + x) * 224 + dv * 8]) =
          *reinterpret_cast<const bf16x8*>(&c_sh[x][dv * 8]);
    }
  }

  gbar(bar, 512u);

  // ===================== P1: conv1 =========================================
  {
    unsigned short(*a_sh)[7920] = (unsigned short(*)[7920])smem;  // 2x15840 B
    const bf16x8* pwv = (const bf16x8*)pw1;
    const bf16x8 zero = {0, 0, 0, 0, 0, 0, 0, 0};
    const int m0 = (wv >> 1) * 32;
    const int n0 = (wv & 1) * 32;

    long goff[4];
    int laddr[4];
    bool gvalid[4], lvalid[4];
#pragma unroll
    for (int it = 0; it < 4; ++it) {
      const int i = tid + it * 256;
      lvalid[it] = i < 792;  // 3*66*4
      const int row = i / 264;
      const int rem = i % 264;
      const int xx = rem >> 2;
      const int q = rem & 3;
      const int gy = y + row - 1;
      const int gx = x0 - 1 + xx;
      gvalid[it] = lvalid[it] && gy >= 0 && gy < HH && gx >= 0 && gx < WW;
      goff[it] = gvalid[it] ? (long)(gy * WW + gx) * 224 + q * 8 : 0;
      laddr[it] = (row * 66 + xx) * 40 + q * 8;
    }

    f32x4 acc[2][2];
#pragma unroll
    for (int i = 0; i < 2; ++i)
#pragma unroll
      for (int jx = 0; jx < 2; ++jx) acc[i][jx] = 0.f;

    bf16x8 stg[4];
#pragma unroll
    for (int it = 0; it < 4; ++it)
      stg[it] = gvalid[it]
                    ? *reinterpret_cast<const bf16x8*>(&cost_t[goff[it]])
                    : zero;
#pragma unroll
    for (int it = 0; it < 4; ++it)
      if (lvalid[it])
        *reinterpret_cast<bf16x8*>(&a_sh[0][laddr[it]]) = stg[it];
    __syncthreads();

    for (int chunk = 0; chunk < 7; ++chunk) {
      const int buf = chunk & 1;
      if (chunk < 6) {
#pragma unroll
        for (int it = 0; it < 4; ++it)
          stg[it] = gvalid[it] ? *reinterpret_cast<const bf16x8*>(
                                     &cost_t[goff[it] + (chunk + 1) * 32])
                               : zero;
      }
      const bf16x8* av = (const bf16x8*)a_sh[buf];
#pragma unroll
      for (int pos = 0; pos < 9; ++pos) {
        const int ky = pos / 3;
        const int kx = pos % 3;
        const int bbase = ((chunk * 9 + pos) * 4 + kg) * 64;
        const bf16x8 b0v = pwv[bbase + n0 + col];
        const bf16x8 b1v = pwv[bbase + n0 + 16 + col];
        const bf16x8 a0v = av[(ky * 66 + m0 + col + kx) * 5 + kg];
        const bf16x8 a1v = av[(ky * 66 + m0 + 16 + col + kx) * 5 + kg];
        acc[0][0] = __builtin_amdgcn_mfma_f32_16x16x32_bf16(a0v, b0v, acc[0][0], 0, 0, 0);
        acc[0][1] = __builtin_amdgcn_mfma_f32_16x16x32_bf16(a0v, b1v, acc[0][1], 0, 0, 0);
        acc[1][0] = __builtin_amdgcn_mfma_f32_16x16x32_bf16(a1v, b0v, acc[1][0], 0, 0, 0);
        acc[1][1] = __builtin_amdgcn_mfma_f32_16x16x32_bf16(a1v, b1v, acc[1][1], 0, 0, 0);
      }
      if (chunk < 6) {
#pragma unroll
        for (int it = 0; it < 4; ++it)
          if (lvalid[it])
            *reinterpret_cast<bf16x8*>(&a_sh[buf ^ 1][laddr[it]]) = stg[it];
        __syncthreads();
      }
    }

#pragma unroll
    for (int nf = 0; nf < 2; ++nf) {
      const int c = n0 + nf * 16 + col;
      const float inv = rsqrtf(v1[c] + 1e-5f);
      const float sc = g1[c] * inv;
      const float sh = be1[c] - m1[c] * sc;
      const float bb = b1[c];
#pragma unroll
      for (int mf = 0; mf < 2; ++mf) {
#pragma unroll
        for (int rr = 0; rr < 4; ++rr) {
          const int m = m0 + mf * 16 + kg * 4 + rr;
          float vv = (acc[mf][nf][rr] + bb) * sc + sh;
          vv = fmaxf(vv, 0.f);
          o1t[((y * WW + x0 + m) << 6) + c] = f2bf(vv);
        }
      }
    }
  }

  gbar(bar + 16, 512u);

  // ===================== P2: conv2 =========================================
  {
    char* const ab = smem;  // 3*66*64 shorts = 25344 B, XOR-swizzled
    const bf16x8* pbv = (const bf16x8*)pb2;
    const int m0 = (wv >> 1) * 32;
    const int n0 = (wv & 1) * 16;

    f32x4 acc[2];
    acc[0] = 0.f;
    acc[1] = 0.f;

    for (int i = tid; i < 1584; i += 256) {  // 3*66*8
      const int r = i >> 3;
      const int q = i & 7;
      const int rowy = r / 66;
      const int xx = r % 66;
      const int gy = y + rowy - 1;
      const int gx = x0 - 1 + xx;
      bf16x8 v = {0, 0, 0, 0, 0, 0, 0, 0};
      if (gy >= 0 && gy < HH && gx >= 0 && gx < WW)
        v = *reinterpret_cast<const bf16x8*>(
            &o1t[((gy * WW + gx) << 6) + q * 8]);
      const int byte = ((r << 7) + (q << 4)) ^ ((r & 7) << 4);
      *reinterpret_cast<bf16x8*>(ab + byte) = v;
    }
    __syncthreads();

#pragma unroll
    for (int pos = 0; pos < 9; ++pos) {
      const int ky = pos / 3;
      const int kx = pos % 3;
#pragma unroll
      for (int kc = 0; kc < 2; ++kc) {
        const bf16x8 bv = pbv[((pos * 2 + kc) * 4 + kg) * 32 + n0 + col];
#pragma unroll
        for (int mf = 0; mf < 2; ++mf) {
          const int r = ky * 66 + m0 + mf * 16 + col + kx;
          const int byte = ((r << 7) + (kc << 6) + (kg << 4)) ^ ((r & 7) << 4);
          const bf16x8 av = *reinterpret_cast<const bf16x8*>(ab + byte);
          acc[mf] =
              __builtin_amdgcn_mfma_f32_16x16x32_bf16(av, bv, acc[mf], 0, 0, 0);
        }
      }
    }

    const int c = n0 + col;
    const float inv = rsqrtf(v2[c] + 1e-5f);
    const float sc = g2[c] * inv;
    const float sh = be2[c] - m2[c] * sc;
    const float bb = b2[c];
#pragma unroll
    for (int mf = 0; mf < 2; ++mf) {
#pragma unroll
      for (int rr = 0; rr < 4; ++rr) {
        const int m = m0 + mf * 16 + kg * 4 + rr;
        float vv = (acc[mf][rr] + bb) * sc + sh;
        vv = fmaxf(vv, 0.f);
        o2t[((y * WW + x0 + m) << 5) + c] = f2bf(vv);
      }
    }
  }

  gbar(bar + 32, 512u);

  // ===================== P3: conv3 =========================================
  {
    char* const ab = smem;  // 3*66*32 shorts = 12672 B
    const bf16x8* pbv = (const bf16x8*)pb3;
    const int m0 = wv * 16;

    f32x4 acc = 0.f;

    for (int i = tid; i < 792; i += 256) {  // 3*66*4
      const int r = i >> 2;
      const int q = i & 3;
      const int rowy = r / 66;
      const int xx = r % 66;
      const int gy = y + rowy - 1;
      const int gx = x0 - 1 + xx;
      bf16x8 v = {0, 0, 0, 0, 0, 0, 0, 0};
      if (gy >= 0 && gy < HH && gx >= 0 && gx < WW)
        v = *reinterpret_cast<const bf16x8*>(
            &o2t[((gy * WW + gx) << 5) + q * 8]);
      const int byte = ((r << 6) + (q << 4)) ^ ((r & 3) << 4);
      *reinterpret_cast<bf16x8*>(ab + byte) = v;
    }
    __syncthreads();

#pragma unroll
    for (int pos = 0; pos < 9; ++pos) {
      const int ky = pos / 3;
      const int kx = pos % 3;
      const bf16x8 bv = pbv[(pos * 4 + kg) * 16 + col];
      const int r = ky * 66 + m0 + col + kx;
      const int byte = ((r << 6) + (kg << 4)) ^ ((r & 3) << 4);
      const bf16x8 av = *reinterpret_cast<const bf16x8*>(ab + byte);
      acc = __builtin_amdgcn_mfma_f32_16x16x32_bf16(av, bv, acc, 0, 0, 0);
    }

    if (col < 8) {
      const int c = col;
      const float inv = rsqrtf(v3[c] + 1e-5f);
      const float sc = g3[c] * inv;
      const float sh = be3[c] - m3[c] * sc;
      const float bb = b3[c];
#pragma unroll
      for (int rr = 0; rr < 4; ++rr) {
        const int m = m0 + kg * 4 + rr;
        float vv = (acc[rr] + bb) * sc + sh;
        vv = fmaxf(vv, 0.f);
        o3t[((y * WW + x0 + m) << 3) + c] = f2bf(vv);
      }
    }
  }

  gbar(bar + 48, 512u);

  // ===================== P4: conv4 (64 px/block) ===========================
  if (tid < 64) {
    const int p = bid * 64 + tid;
    const int py = p >> 8;
    const int px = p & 255;

    float wr[3][3][8];
#pragma unroll
    for (int ci = 0; ci < 8; ++ci)
#pragma unroll
      for (int ky = 0; ky < 3; ++ky)
#pragma unroll
        for (int kx = 0; kx < 3; ++kx)
          wr[ky][kx][ci] = w4[(ci * 3 + ky) * 3 + kx];

    float acc = b4[0];
#pragma unroll
    for (int ky = 0; ky < 3; ++ky) {
      const int gy = py + ky - 1;
      if (gy < 0 || gy >= HH) continue;
#pragma unroll
      for (int kx = 0; kx < 3; ++kx) {
        const int gx = px + kx - 1;
        if (gx < 0 || gx >= WW) continue;
        const bf16x8 v =
            *reinterpret_cast<const bf16x8*>(&o3t[((gy << 8) + gx) << 3]);
#pragma unroll
        for (int ci = 0; ci < 8; ++ci) acc += bf2f(v[ci]) * wr[ky][kx][ci];
      }
    }
    out[p] = acc;
  }
}

// ---------------------------------------------------------------------------
extern "C" void kernel_launch(void* const* d_in, const int* in_sizes, int n_in,
                              void* d_out, int out_size, void* d_ws,
                              size_t ws_size, hipStream_t stream) {
  const float* left = (const float*)d_in[0];
  const float* right = (const float*)d_in[1];
  const float* w1 = (const float*)d_in[2];
  const float* b1 = (const float*)d_in[3];
  const float* g1 = (const float*)d_in[4];
  const float* be1 = (const float*)d_in[5];
  const float* m1 = (const float*)d_in[6];
  const float* v1 = (const float*)d_in[7];
  const float* w2 = (const float*)d_in[8];
  const float* b2 = (const float*)d_in[9];
  const float* g2 = (const float*)d_in[10];
  const float* be2 = (const float*)d_in[11];
  const float* m2 = (const float*)d_in[12];
  const float* v2 = (const float*)d_in[13];
  const float* w3 = (const float*)d_in[14];
  const float* b3 = (const float*)d_in[15];
  const float* g3 = (const float*)d_in[16];
  const float* be3 = (const float*)d_in[17];
  const float* m3 = (const float*)d_in[18];
  const float* v3 = (const float*)d_in[19];
  const float* w4 = (const float*)d_in[20];
  const float* b4 = (const float*)d_in[21];

  // Workspace:
  //  [0, 14680064)   cost_t bf16 [128][256][224]
  //  region: +0 pw1 (262144) | +262144 pb2 (65536) | +327680 pb3 (65536)
  //          +393216  o1_t bf16 [128][256][64] (4194304)
  //          +4587520 o2_t bf16 [128][256][32] (2097152)
  //          +6684672 o3_t bf16 [128][256][8]  (524288)
  //  [33554432, +256) grid-barrier counters (zeroed per call)
  char* ws = (char*)d_ws;
  unsigned short* cost_t = (unsigned short*)ws;
  char* region = ws + 14680064;
  unsigned short* pw1 = (unsigned short*)(region + 0);
  unsigned short* pb2 = (unsigned short*)(region + 262144);
  unsigned short* pb3 = (unsigned short*)(region + 327680);
  unsigned short* o1t = (unsigned short*)(region + 393216);
  unsigned short* o2t = (unsigned short*)(region + 4587520);
  unsigned short* o3t = (unsigned short*)(region + 6684672);
  unsigned int* bar = (unsigned int*)(ws + 33554432);
  float* o4 = (float*)d_out;

  hipMemsetAsync(bar, 0, 256, stream);
  mega_kernel<<<512, 256, 0, stream>>>(
      left, right, w1, b1, g1, be1, m1, v1, w2, b2, g2, be2, m2, v2, w3, b3,
      g3, be3, m3, v3, w4, b4, cost_t, pw1, pb2, pb3, o1t, o2t, o3t, o4, bar);
}

// Round 8
// 51.398 us; speedup vs baseline: 5.4079x; 4.7318x over previous
//
#include <hip/hip_runtime.h>

#define HH 128
#define WW 256
#define CV_C 32
#define DISP 200

typedef __attribute__((ext_vector_type(4))) float f32x4;
typedef __attribute__((ext_vector_type(8))) short bf16x8;

__device__ inline unsigned short f2bf(float f) {
  unsigned int u = __float_as_uint(f);
  u = (u + 0x7FFFu + ((u >> 16) & 1u)) >> 16;  // RNE
  return (unsigned short)u;
}

__device__ inline float bf2f(short s) {
  return __uint_as_float(((unsigned int)(unsigned short)s) << 16);
}

// XCD-consistent job mapping for 512-block kernels (4 x-tiles x 128 y):
// XCD k = bid&7 owns y in [k*16, k*16+16) across ALL kernels, so each row's
// producer and consumer (and y-halo neighbors) share one XCD's L2.
#define MAP_YX4()                                   \
  const int slot = bid >> 3;                        \
  const int y = ((bid & 7) << 4) + (slot & 15);     \
  const int x0 = (slot >> 4) << 6;

// ---------------------------------------------------------------------------
// K1: blocks 0..511 cost-volume MFMA (critical path first), 512..1105 packs.
// CV: cost[d,y,x] = sum_c L[c,y,x]*R[c,y,x+d-200] -> cost_t bf16 [128][256][224]
// ---------------------------------------------------------------------------
__global__ __launch_bounds__(256) void k1_cv_pack(
    const float* __restrict__ left, const float* __restrict__ right,
    const float* __restrict__ w1, const float* __restrict__ w2,
    const float* __restrict__ w3, unsigned short* __restrict__ pw1,
    unsigned short* __restrict__ pb2, unsigned short* __restrict__ pb3,
    unsigned short* __restrict__ cost_t) {
  __shared__ unsigned short r_sh[272][40];  // 21760 B
  __shared__ unsigned short l_hi[64][40];   // 5120 B
  __shared__ unsigned short l_lo[64][40];   // 5120 B
  __shared__ unsigned short c_sh[64][224];  // 28672 B
  const int bid = blockIdx.x;
  const int tid = threadIdx.x;

  if (bid >= 512) {  // ---- weight packing ----
    const int b = bid - 512;
    if (b < 504) {  // pw1[chunk 7][pos 9][kg 4][n 64][j 8]
      const int idx = b * 256 + tid;
      const int j = idx & 7;
      const int n = (idx >> 3) & 63;
      const int kg = (idx >> 9) & 3;
      const int cp = idx >> 11;
      const int pos = cp % 9;
      const int chunk = cp / 9;
      const int ci = chunk * 32 + kg * 8 + j;
      float v = 0.f;
      if (ci < 200) v = w1[(n * 200 + ci) * 9 + pos];
      pw1[idx] = f2bf(v);
    } else if (b < 576) {  // pb2[pos 9][kc 2][kg 4][n 32][j 8]
      const int idx = (b - 504) * 256 + tid;
      const int j = idx & 7;
      const int n = (idx >> 3) & 31;
      const int kg = (idx >> 8) & 3;
      const int kc = (idx >> 10) & 1;
      const int pos = idx >> 11;
      const int ci = kc * 32 + kg * 8 + j;
      pb2[idx] = f2bf(w2[(n * 64 + ci) * 9 + pos]);
    } else {  // pb3[pos 9][kg 4][n 16(8 real)][j 8]
      const int idx = (b - 576) * 256 + tid;
      const int j = idx & 7;
      const int n = (idx >> 3) & 15;
      const int kg = (idx >> 7) & 3;
      const int pos = idx >> 9;
      const int ci = kg * 8 + j;
      float v = 0.f;
      if (n < 8) v = w3[(n * 32 + ci) * 9 + pos];
      pb3[idx] = f2bf(v);
    }
    return;
  }

  // ---- cost volume (round-4 proven body) ----
  MAP_YX4();
  const int lane = tid & 63;
  const int wv = tid >> 6;
  const int col = lane & 15;
  const int kg = lane >> 4;

  for (int c = wv; c < CV_C; c += 4) {
    const float v = left[(c * HH + y) * WW + x0 + lane];
    const unsigned short h = f2bf(v);
    l_hi[lane][c] = h;
    l_lo[lane][c] = f2bf(v - bf2f(h));
  }
  for (int c = wv; c < CV_C; c += 4) {
    for (int pq = 0; pq < 320; pq += 64) {
      const int p = pq + lane;
      if (p < 272) {
        const int xp = x0 - 208 + p;
        float v = (xp >= 0) ? right[(c * HH + y) * WW + xp] : 0.f;
        r_sh[p][c] = f2bf(v);
      }
    }
  }
  {
    bf16x8 z = {0, 0, 0, 0, 0, 0, 0, 0};
    bf16x8* cz = (bf16x8*)c_sh;
#pragma unroll
    for (int k = 0; k < 7; ++k) cz[k * 256 + tid] = z;
  }
  __syncthreads();

  const bf16x8 b_hi = *(const bf16x8*)&l_hi[16 * wv + col][kg * 8];
  const bf16x8 b_lo = *(const bf16x8*)&l_lo[16 * wv + col][kg * 8];

  for (int t = 0; t < 14; ++t) {
    const int pq = 16 * (wv - t) + 208;
    const bf16x8 a_r = *(const bf16x8*)&r_sh[pq + col][kg * 8];
    f32x4 acc = {0.f, 0.f, 0.f, 0.f};
    acc = __builtin_amdgcn_mfma_f32_16x16x32_bf16(a_r, b_hi, acc, 0, 0, 0);
    acc = __builtin_amdgcn_mfma_f32_16x16x32_bf16(a_r, b_lo, acc, 0, 0, 0);
#pragma unroll
    for (int r = 0; r < 4; ++r) {
      const int d = 200 - 16 * t + kg * 4 + r - col;
      if (d >= 0 && d < DISP) c_sh[16 * wv + col][d] = f2bf(acc[r]);
    }
  }
  __syncthreads();

#pragma unroll
  for (int k = 0; k < 7; ++k) {
    const int s = k * 256 + tid;
    const int x = s / 28;
    const int dv = s - x * 28;
    *reinterpret_cast<bf16x8*>(&cost_t[(y * WW + x0 + x) * 224 + dv * 8]) =
        *reinterpret_cast<const bf16x8*>(&c_sh[x][dv * 8]);
  }
}

// ---------------------------------------------------------------------------
// K2: conv1 implicit GEMM bf16 MFMA, double-buffered A staging (round-4 body).
// ---------------------------------------------------------------------------
__global__ __launch_bounds__(256) void conv1_mfma_kernel(
    const unsigned short* __restrict__ cost_t,  // [128][256][224]
    const unsigned short* __restrict__ pw,      // [7][9][4][64][8]
    const float* __restrict__ bias, const float* __restrict__ gam,
    const float* __restrict__ bet, const float* __restrict__ mean,
    const float* __restrict__ var, unsigned short* __restrict__ out_t) {
  __shared__ unsigned short a_sh[2][3 * 66 * 40];  // 31680 B
  const int bid = blockIdx.x;
  const int tid = threadIdx.x;
  MAP_YX4();
  const int lane = tid & 63;
  const int wv = tid >> 6;
  const int m0 = (wv >> 1) * 32;
  const int n0 = (wv & 1) * 32;
  const int col = lane & 15;
  const int kg = lane >> 4;

  long goff[4];
  int laddr[4];
  bool gvalid[4], lvalid[4];
#pragma unroll
  for (int it = 0; it < 4; ++it) {
    const int i = tid + it * 256;
    lvalid[it] = i < 792;  // 3*66*4
    const int row = i / 264;
    const int rem = i % 264;
    const int xx = rem >> 2;
    const int q = rem & 3;
    const int gy = y + row - 1;
    const int gx = x0 - 1 + xx;
    gvalid[it] = lvalid[it] && gy >= 0 && gy < HH && gx >= 0 && gx < WW;
    goff[it] = gvalid[it] ? (long)(gy * WW + gx) * 224 + q * 8 : 0;
    laddr[it] = (row * 66 + xx) * 40 + q * 8;
  }

  f32x4 acc[2][2];
#pragma unroll
  for (int i = 0; i < 2; ++i)
#pragma unroll
    for (int jx = 0; jx < 2; ++jx) acc[i][jx] = 0.f;

  const bf16x8* pwv = (const bf16x8*)pw;
  const bf16x8 zero = {0, 0, 0, 0, 0, 0, 0, 0};
  bf16x8 stg[4];

#pragma unroll
  for (int it = 0; it < 4; ++it)
    stg[it] = gvalid[it] ? *reinterpret_cast<const bf16x8*>(&cost_t[goff[it]])
                         : zero;
#pragma unroll
  for (int it = 0; it < 4; ++it)
    if (lvalid[it]) *reinterpret_cast<bf16x8*>(&a_sh[0][laddr[it]]) = stg[it];
  __syncthreads();

  for (int chunk = 0; chunk < 7; ++chunk) {
    const int buf = chunk & 1;
    if (chunk < 6) {
#pragma unroll
      for (int it = 0; it < 4; ++it)
        stg[it] = gvalid[it] ? *reinterpret_cast<const bf16x8*>(
                                   &cost_t[goff[it] + (chunk + 1) * 32])
                             : zero;
    }
    const bf16x8* av = (const bf16x8*)a_sh[buf];
#pragma unroll
    for (int pos = 0; pos < 9; ++pos) {
      const int ky = pos / 3;
      const int kx = pos % 3;
      const int bbase = ((chunk * 9 + pos) * 4 + kg) * 64;
      const bf16x8 b0v = pwv[bbase + n0 + col];
      const bf16x8 b1v = pwv[bbase + n0 + 16 + col];
      const bf16x8 a0v = av[(ky * 66 + m0 + col + kx) * 5 + kg];
      const bf16x8 a1v = av[(ky * 66 + m0 + 16 + col + kx) * 5 + kg];
      acc[0][0] = __builtin_amdgcn_mfma_f32_16x16x32_bf16(a0v, b0v, acc[0][0], 0, 0, 0);
      acc[0][1] = __builtin_amdgcn_mfma_f32_16x16x32_bf16(a0v, b1v, acc[0][1], 0, 0, 0);
      acc[1][0] = __builtin_amdgcn_mfma_f32_16x16x32_bf16(a1v, b0v, acc[1][0], 0, 0, 0);
      acc[1][1] = __builtin_amdgcn_mfma_f32_16x16x32_bf16(a1v, b1v, acc[1][1], 0, 0, 0);
    }
    if (chunk < 6) {
#pragma unroll
      for (int it = 0; it < 4; ++it)
        if (lvalid[it])
          *reinterpret_cast<bf16x8*>(&a_sh[buf ^ 1][laddr[it]]) = stg[it];
      __syncthreads();
    }
  }

#pragma unroll
  for (int nf = 0; nf < 2; ++nf) {
    const int c = n0 + nf * 16 + col;
    const float inv = rsqrtf(var[c] + 1e-5f);
    const float sc = gam[c] * inv;
    const float sh = bet[c] - mean[c] * sc;
    const float bb = bias[c];
#pragma unroll
    for (int mf = 0; mf < 2; ++mf) {
#pragma unroll
      for (int rr = 0; rr < 4; ++rr) {
        const int m = m0 + mf * 16 + kg * 4 + rr;
        float vv = (acc[mf][nf][rr] + bb) * sc + sh;
        vv = fmaxf(vv, 0.f);
        out_t[((y * WW + x0 + m) << 6) + c] = f2bf(vv);
      }
    }
  }
}

// ---------------------------------------------------------------------------
// K3: conv2 64->32, NHWC bf16, XOR-swizzled A-tile (round-4 body).
// ---------------------------------------------------------------------------
__global__ __launch_bounds__(256) void conv2_mfma_kernel(
    const unsigned short* __restrict__ in_t,  // [128][256][64]
    const unsigned short* __restrict__ pb,    // [9][2][4][32][8]
    const float* __restrict__ bias, const float* __restrict__ gam,
    const float* __restrict__ bet, const float* __restrict__ mean,
    const float* __restrict__ var, unsigned short* __restrict__ out_t) {
  __shared__ unsigned short a_sh[3 * 66 * 64];  // 25344 B
  char* const ab = (char*)a_sh;
  const int bid = blockIdx.x;
  const int tid = threadIdx.x;
  MAP_YX4();
  const int lane = tid & 63;
  const int wv = tid >> 6;
  const int m0 = (wv >> 1) * 32;
  const int n0 = (wv & 1) * 16;
  const int col = lane & 15;
  const int kg = lane >> 4;

  f32x4 acc[2];
  acc[0] = 0.f;
  acc[1] = 0.f;

  for (int i = tid; i < 1584; i += 256) {  // 3*66*8
    const int r = i >> 3;
    const int q = i & 7;
    const int rowy = r / 66;
    const int xx = r % 66;
    const int gy = y + rowy - 1;
    const int gx = x0 - 1 + xx;
    bf16x8 v = {0, 0, 0, 0, 0, 0, 0, 0};
    if (gy >= 0 && gy < HH && gx >= 0 && gx < WW)
      v = *reinterpret_cast<const bf16x8*>(&in_t[((gy * WW + gx) << 6) + q * 8]);
    const int byte = ((r << 7) + (q << 4)) ^ ((r & 7) << 4);
    *reinterpret_cast<bf16x8*>(ab + byte) = v;
  }
  __syncthreads();

  const bf16x8* pbv = (const bf16x8*)pb;
#pragma unroll
  for (int pos = 0; pos < 9; ++pos) {
    const int ky = pos / 3;
    const int kx = pos % 3;
#pragma unroll
    for (int kc = 0; kc < 2; ++kc) {
      const bf16x8 bv = pbv[((pos * 2 + kc) * 4 + kg) * 32 + n0 + col];
#pragma unroll
      for (int mf = 0; mf < 2; ++mf) {
        const int r = ky * 66 + m0 + mf * 16 + col + kx;
        const int byte = ((r << 7) + (kc << 6) + (kg << 4)) ^ ((r & 7) << 4);
        const bf16x8 av = *reinterpret_cast<const bf16x8*>(ab + byte);
        acc[mf] = __builtin_amdgcn_mfma_f32_16x16x32_bf16(av, bv, acc[mf], 0, 0, 0);
      }
    }
  }

  const int c = n0 + col;
  const float inv = rsqrtf(var[c] + 1e-5f);
  const float sc = gam[c] * inv;
  const float sh = bet[c] - mean[c] * sc;
  const float bb = bias[c];
#pragma unroll
  for (int mf = 0; mf < 2; ++mf) {
#pragma unroll
    for (int rr = 0; rr < 4; ++rr) {
      const int m = m0 + mf * 16 + kg * 4 + rr;
      float vv = (acc[mf][rr] + bb) * sc + sh;
      vv = fmaxf(vv, 0.f);
      out_t[((y * WW + x0 + m) << 5) + c] = f2bf(vv);
    }
  }
}

// ---------------------------------------------------------------------------
// K4: conv3 32->8 (N padded to 16), NHWC bf16 (round-4 body).
// ---------------------------------------------------------------------------
__global__ __launch_bounds__(256) void conv3_mfma_kernel(
    const unsigned short* __restrict__ in_t,  // [128][256][32]
    const unsigned short* __restrict__ pb,    // [9][4][16][8]
    const float* __restrict__ bias, const float* __restrict__ gam,
    const float* __restrict__ bet, const float* __restrict__ mean,
    const float* __restrict__ var, unsigned short* __restrict__ out_t) {
  __shared__ unsigned short a_sh[3 * 66 * 32];  // 12672 B
  char* const ab = (char*)a_sh;
  const int bid = blockIdx.x;
  const int tid = threadIdx.x;
  MAP_YX4();
  const int lane = tid & 63;
  const int wv = tid >> 6;
  const int m0 = wv * 16;
  const int col = lane & 15;
  const int kg = lane >> 4;

  f32x4 acc = 0.f;

  for (int i = tid; i < 792; i += 256) {  // 3*66*4
    const int r = i >> 2;
    const int q = i & 3;
    const int rowy = r / 66;
    const int xx = r % 66;
    const int gy = y + rowy - 1;
    const int gx = x0 - 1 + xx;
    bf16x8 v = {0, 0, 0, 0, 0, 0, 0, 0};
    if (gy >= 0 && gy < HH && gx >= 0 && gx < WW)
      v = *reinterpret_cast<const bf16x8*>(&in_t[((gy * WW + gx) << 5) + q * 8]);
    const int byte = ((r << 6) + (q << 4)) ^ ((r & 3) << 4);
    *reinterpret_cast<bf16x8*>(ab + byte) = v;
  }
  __syncthreads();

  const bf16x8* pbv = (const bf16x8*)pb;
#pragma unroll
  for (int pos = 0; pos < 9; ++pos) {
    const int ky = pos / 3;
    const int kx = pos % 3;
    const bf16x8 bv = pbv[(pos * 4 + kg) * 16 + col];
    const int r = ky * 66 + m0 + col + kx;
    const int byte = ((r << 6) + (kg << 4)) ^ ((r & 3) << 4);
    const bf16x8 av = *reinterpret_cast<const bf16x8*>(ab + byte);
    acc = __builtin_amdgcn_mfma_f32_16x16x32_bf16(av, bv, acc, 0, 0, 0);
  }

  if (col < 8) {
    const int c = col;
    const float inv = rsqrtf(var[c] + 1e-5f);
    const float sc = gam[c] * inv;
    const float sh = bet[c] - mean[c] * sc;
    const float bb = bias[c];
#pragma unroll
    for (int rr = 0; rr < 4; ++rr) {
      const int m = m0 + kg * 4 + rr;
      float vv = (acc[rr] + bb) * sc + sh;
      vv = fmaxf(vv, 0.f);
      out_t[((y * WW + x0 + m) << 3) + c] = f2bf(vv);
    }
  }
}

// ---------------------------------------------------------------------------
// K5: conv4 8->1, per-pixel direct; 128 blocks, one y-row each (XCD-mapped).
// ---------------------------------------------------------------------------
__global__ __launch_bounds__(256) void conv4_kernel(
    const unsigned short* __restrict__ in_t, const float* __restrict__ w4,
    const float* __restrict__ b4, float* __restrict__ out) {
  const int bid = blockIdx.x;
  const int y = ((bid & 7) << 4) + (bid >> 3);  // XCD k owns y in [16k,16k+16)
  const int x = threadIdx.x;

  float wr[3][3][8];
#pragma unroll
  for (int ci = 0; ci < 8; ++ci)
#pragma unroll
    for (int ky = 0; ky < 3; ++ky)
#pragma unroll
      for (int kx = 0; kx < 3; ++kx) wr[ky][kx][ci] = w4[(ci * 3 + ky) * 3 + kx];

  float acc = b4[0];
#pragma unroll
  for (int ky = 0; ky < 3; ++ky) {
    const int gy = y + ky - 1;
    if (gy < 0 || gy >= HH) continue;
#pragma unroll
    for (int kx = 0; kx < 3; ++kx) {
      const int gx = x + kx - 1;
      if (gx < 0 || gx >= WW) continue;
      const bf16x8 v =
          *reinterpret_cast<const bf16x8*>(&in_t[((gy << 8) + gx) << 3]);
#pragma unroll
      for (int ci = 0; ci < 8; ++ci) acc += bf2f(v[ci]) * wr[ky][kx][ci];
    }
  }
  out[y * WW + x] = acc;
}

// ---------------------------------------------------------------------------
extern "C" void kernel_launch(void* const* d_in, const int* in_sizes, int n_in,
                              void* d_out, int out_size, void* d_ws,
                              size_t ws_size, hipStream_t stream) {
  const float* left = (const float*)d_in[0];
  const float* right = (const float*)d_in[1];
  const float* w1 = (const float*)d_in[2];
  const float* b1 = (const float*)d_in[3];
  const float* g1 = (const float*)d_in[4];
  const float* be1 = (const float*)d_in[5];
  const float* m1 = (const float*)d_in[6];
  const float* v1 = (const float*)d_in[7];
  const float* w2 = (const float*)d_in[8];
  const float* b2 = (const float*)d_in[9];
  const float* g2 = (const float*)d_in[10];
  const float* be2 = (const float*)d_in[11];
  const float* m2 = (const float*)d_in[12];
  const float* v2 = (const float*)d_in[13];
  const float* w3 = (const float*)d_in[14];
  const float* b3 = (const float*)d_in[15];
  const float* g3 = (const float*)d_in[16];
  const float* be3 = (const float*)d_in[17];
  const float* m3 = (const float*)d_in[18];
  const float* v3 = (const float*)d_in[19];
  const float* w4 = (const float*)d_in[20];
  const float* b4 = (const float*)d_in[21];

  // Workspace:
  //  [0, 14680064)   cost_t bf16 [128][256][224]
  //  region: +0 pw1 (262144) | +262144 pb2 (65536) | +327680 pb3 (65536)
  //          +393216  o1_t bf16 [128][256][64] (4194304)
  //          +4587520 o2_t bf16 [128][256][32] (2097152)
  //          +6684672 o3_t bf16 [128][256][8]  (524288)
  char* ws = (char*)d_ws;
  unsigned short* cost_t = (unsigned short*)ws;
  char* region = ws + 14680064;
  unsigned short* pw1 = (unsigned short*)(region + 0);
  unsigned short* pb2 = (unsigned short*)(region + 262144);
  unsigned short* pb3 = (unsigned short*)(region + 327680);
  unsigned short* o1t = (unsigned short*)(region + 393216);
  unsigned short* o2t = (unsigned short*)(region + 4587520);
  unsigned short* o3t = (unsigned short*)(region + 6684672);
  float* o4 = (float*)d_out;

  k1_cv_pack<<<1106, 256, 0, stream>>>(left, right, w1, w2, w3, pw1, pb2, pb3,
                                       cost_t);
  conv1_mfma_kernel<<<512, 256, 0, stream>>>(cost_t, pw1, b1, g1, be1, m1, v1,
                                             o1t);
  conv2_mfma_kernel<<<512, 256, 0, stream>>>(o1t, pb2, b2, g2, be2, m2, v2,
                                             o2t);
  conv3_mfma_kernel<<<512, 256, 0, stream>>>(o2t, pb3, b3, g3, be3, m3, v3,
                                             o3t);
  conv4_kernel<<<128, 256, 0, stream>>>(o3t, w4, b4, o4);
}

// Round 9
// 49.290 us; speedup vs baseline: 5.6392x; 1.0428x over previous
//
#include <hip/hip_runtime.h>

#define HH 128
#define WW 256
#define CV_C 32
#define DISP 200

typedef __attribute__((ext_vector_type(4))) float f32x4;
typedef __attribute__((ext_vector_type(8))) short bf16x8;

__device__ inline unsigned short f2bf(float f) {
  unsigned int u = __float_as_uint(f);
  u = (u + 0x7FFFu + ((u >> 16) & 1u)) >> 16;  // RNE
  return (unsigned short)u;
}

__device__ inline float bf2f(short s) {
  return __uint_as_float(((unsigned int)(unsigned short)s) << 16);
}

// XCD-consistent job mapping for 512-block kernels (4 x-tiles x 128 y):
// XCD k = bid&7 owns y in [k*16, k*16+16) across ALL kernels, so each row's
// producer and consumer (and y-halo neighbors) share one XCD's L2.
#define MAP_YX4()                                   \
  const int slot = bid >> 3;                        \
  const int y = ((bid & 7) << 4) + (slot & 15);     \
  const int x0 = (slot >> 4) << 6;

// ---------------------------------------------------------------------------
// K1: blocks 0..511 cost-volume MFMA (critical path first), 512..1105 packs.
// CV: cost[d,y,x] = sum_c L[c,y,x]*R[c,y,x+d-200] -> cost_t bf16 [128][256][224]
// ---------------------------------------------------------------------------
__global__ __launch_bounds__(256) void k1_cv_pack(
    const float* __restrict__ left, const float* __restrict__ right,
    const float* __restrict__ w1, const float* __restrict__ w2,
    const float* __restrict__ w3, unsigned short* __restrict__ pw1,
    unsigned short* __restrict__ pb2, unsigned short* __restrict__ pb3,
    unsigned short* __restrict__ cost_t) {
  __shared__ unsigned short r_sh[272][40];  // 21760 B
  __shared__ unsigned short l_hi[64][40];   // 5120 B
  __shared__ unsigned short l_lo[64][40];   // 5120 B
  __shared__ unsigned short c_sh[64][224];  // 28672 B
  const int bid = blockIdx.x;
  const int tid = threadIdx.x;

  if (bid >= 512) {  // ---- weight packing ----
    const int b = bid - 512;
    if (b < 504) {  // pw1[chunk 7][pos 9][kg 4][n 64][j 8]
      const int idx = b * 256 + tid;
      const int j = idx & 7;
      const int n = (idx >> 3) & 63;
      const int kg = (idx >> 9) & 3;
      const int cp = idx >> 11;
      const int pos = cp % 9;
      const int chunk = cp / 9;
      const int ci = chunk * 32 + kg * 8 + j;
      float v = 0.f;
      if (ci < 200) v = w1[(n * 200 + ci) * 9 + pos];
      pw1[idx] = f2bf(v);
    } else if (b < 576) {  // pb2[pos 9][kc 2][kg 4][n 32][j 8]
      const int idx = (b - 504) * 256 + tid;
      const int j = idx & 7;
      const int n = (idx >> 3) & 31;
      const int kg = (idx >> 8) & 3;
      const int kc = (idx >> 10) & 1;
      const int pos = idx >> 11;
      const int ci = kc * 32 + kg * 8 + j;
      pb2[idx] = f2bf(w2[(n * 64 + ci) * 9 + pos]);
    } else {  // pb3[pos 9][kg 4][n 16(8 real)][j 8]
      const int idx = (b - 576) * 256 + tid;
      const int j = idx & 7;
      const int n = (idx >> 3) & 15;
      const int kg = (idx >> 7) & 3;
      const int pos = idx >> 9;
      const int ci = kg * 8 + j;
      float v = 0.f;
      if (n < 8) v = w3[(n * 32 + ci) * 9 + pos];
      pb3[idx] = f2bf(v);
    }
    return;
  }

  // ---- cost volume (proven body) ----
  MAP_YX4();
  const int lane = tid & 63;
  const int wv = tid >> 6;
  const int col = lane & 15;
  const int kg = lane >> 4;

  for (int c = wv; c < CV_C; c += 4) {
    const float v = left[(c * HH + y) * WW + x0 + lane];
    const unsigned short h = f2bf(v);
    l_hi[lane][c] = h;
    l_lo[lane][c] = f2bf(v - bf2f(h));
  }
  for (int c = wv; c < CV_C; c += 4) {
    for (int pq = 0; pq < 320; pq += 64) {
      const int p = pq + lane;
      if (p < 272) {
        const int xp = x0 - 208 + p;
        float v = (xp >= 0) ? right[(c * HH + y) * WW + xp] : 0.f;
        r_sh[p][c] = f2bf(v);
      }
    }
  }
  {
    bf16x8 z = {0, 0, 0, 0, 0, 0, 0, 0};
    bf16x8* cz = (bf16x8*)c_sh;
#pragma unroll
    for (int k = 0; k < 7; ++k) cz[k * 256 + tid] = z;
  }
  __syncthreads();

  const bf16x8 b_hi = *(const bf16x8*)&l_hi[16 * wv + col][kg * 8];
  const bf16x8 b_lo = *(const bf16x8*)&l_lo[16 * wv + col][kg * 8];

  for (int t = 0; t < 14; ++t) {
    const int pq = 16 * (wv - t) + 208;
    const bf16x8 a_r = *(const bf16x8*)&r_sh[pq + col][kg * 8];
    f32x4 acc = {0.f, 0.f, 0.f, 0.f};
    acc = __builtin_amdgcn_mfma_f32_16x16x32_bf16(a_r, b_hi, acc, 0, 0, 0);
    acc = __builtin_amdgcn_mfma_f32_16x16x32_bf16(a_r, b_lo, acc, 0, 0, 0);
#pragma unroll
    for (int r = 0; r < 4; ++r) {
      const int d = 200 - 16 * t + kg * 4 + r - col;
      if (d >= 0 && d < DISP) c_sh[16 * wv + col][d] = f2bf(acc[r]);
    }
  }
  __syncthreads();

#pragma unroll
  for (int k = 0; k < 7; ++k) {
    const int s = k * 256 + tid;
    const int x = s / 28;
    const int dv = s - x * 28;
    *reinterpret_cast<bf16x8*>(&cost_t[(y * WW + x0 + x) * 224 + dv * 8]) =
        *reinterpret_cast<const bf16x8*>(&c_sh[x][dv * 8]);
  }
}

// ---------------------------------------------------------------------------
// K2: conv1 implicit GEMM bf16 MFMA. A and B-chunk both staged in LDS
// (single-buffered; next chunk prefetched into VGPRs during MFMAs, written
// after a post-MFMA barrier -> same overlap as dbuf, half the LDS, and the
// per-wave-duplicated weight reads (258MB L2) become one LDS copy (132MB).
// ---------------------------------------------------------------------------
__global__ __launch_bounds__(256) void conv1_mfma_kernel(
    const unsigned short* __restrict__ cost_t,  // [128][256][224]
    const unsigned short* __restrict__ pw,      // [7][9][4][64][8]
    const float* __restrict__ bias, const float* __restrict__ gam,
    const float* __restrict__ bet, const float* __restrict__ mean,
    const float* __restrict__ var, unsigned short* __restrict__ out_t) {
  __shared__ unsigned short a_sh[3 * 66 * 40];     // 15840 B
  __shared__ unsigned short b_sh[9 * 4 * 64 * 8];  // 36864 B (one chunk of pw)
  const int bid = blockIdx.x;
  const int tid = threadIdx.x;
  MAP_YX4();
  const int lane = tid & 63;
  const int wv = tid >> 6;
  const int m0 = (wv >> 1) * 32;
  const int n0 = (wv & 1) * 32;
  const int col = lane & 15;
  const int kg = lane >> 4;

  long goff[4];
  int laddr[4];
  bool gvalid[4], lvalid[4];
#pragma unroll
  for (int it = 0; it < 4; ++it) {
    const int i = tid + it * 256;
    lvalid[it] = i < 792;  // 3*66*4
    const int row = i / 264;
    const int rem = i % 264;
    const int xx = rem >> 2;
    const int q = rem & 3;
    const int gy = y + row - 1;
    const int gx = x0 - 1 + xx;
    gvalid[it] = lvalid[it] && gy >= 0 && gy < HH && gx >= 0 && gx < WW;
    goff[it] = gvalid[it] ? (long)(gy * WW + gx) * 224 + q * 8 : 0;
    laddr[it] = (row * 66 + xx) * 40 + q * 8;
  }

  f32x4 acc[2][2];
#pragma unroll
  for (int i = 0; i < 2; ++i)
#pragma unroll
    for (int jx = 0; jx < 2; ++jx) acc[i][jx] = 0.f;

  const bf16x8* pwv = (const bf16x8*)pw;  // 2304 vec8 slots per chunk
  bf16x8* bsl = (bf16x8*)b_sh;
  const bf16x8 zero = {0, 0, 0, 0, 0, 0, 0, 0};
  bf16x8 stgA[4], stgB[9];

  // prologue: stage chunk 0 (A + B)
#pragma unroll
  for (int it = 0; it < 4; ++it)
    stgA[it] = gvalid[it] ? *reinterpret_cast<const bf16x8*>(&cost_t[goff[it]])
                          : zero;
#pragma unroll
  for (int it = 0; it < 9; ++it) stgB[it] = pwv[tid + it * 256];
#pragma unroll
  for (int it = 0; it < 4; ++it)
    if (lvalid[it]) *reinterpret_cast<bf16x8*>(&a_sh[laddr[it]]) = stgA[it];
#pragma unroll
  for (int it = 0; it < 9; ++it) bsl[tid + it * 256] = stgB[it];
  __syncthreads();

  for (int chunk = 0; chunk < 7; ++chunk) {
    if (chunk < 6) {  // prefetch next chunk into regs (hidden by MFMAs)
#pragma unroll
      for (int it = 0; it < 4; ++it)
        stgA[it] = gvalid[it] ? *reinterpret_cast<const bf16x8*>(
                                    &cost_t[goff[it] + (chunk + 1) * 32])
                              : zero;
      const bf16x8* pwn = pwv + (chunk + 1) * 2304;
#pragma unroll
      for (int it = 0; it < 9; ++it) stgB[it] = pwn[tid + it * 256];
    }
    const bf16x8* av = (const bf16x8*)a_sh;
#pragma unroll
    for (int pos = 0; pos < 9; ++pos) {
      const int ky = pos / 3;
      const int kx = pos % 3;
      const bf16x8 b0v = bsl[(pos * 4 + kg) * 64 + n0 + col];
      const bf16x8 b1v = bsl[(pos * 4 + kg) * 64 + n0 + 16 + col];
      const bf16x8 a0v = av[(ky * 66 + m0 + col + kx) * 5 + kg];
      const bf16x8 a1v = av[(ky * 66 + m0 + 16 + col + kx) * 5 + kg];
      acc[0][0] = __builtin_amdgcn_mfma_f32_16x16x32_bf16(a0v, b0v, acc[0][0], 0, 0, 0);
      acc[0][1] = __builtin_amdgcn_mfma_f32_16x16x32_bf16(a0v, b1v, acc[0][1], 0, 0, 0);
      acc[1][0] = __builtin_amdgcn_mfma_f32_16x16x32_bf16(a1v, b0v, acc[1][0], 0, 0, 0);
      acc[1][1] = __builtin_amdgcn_mfma_f32_16x16x32_bf16(a1v, b1v, acc[1][1], 0, 0, 0);
    }
    if (chunk < 6) {
      __syncthreads();  // all waves done reading a_sh/b_sh for this chunk
#pragma unroll
      for (int it = 0; it < 4; ++it)
        if (lvalid[it]) *reinterpret_cast<bf16x8*>(&a_sh[laddr[it]]) = stgA[it];
#pragma unroll
      for (int it = 0; it < 9; ++it) bsl[tid + it * 256] = stgB[it];
      __syncthreads();  // new chunk visible
    }
  }

#pragma unroll
  for (int nf = 0; nf < 2; ++nf) {
    const int c = n0 + nf * 16 + col;
    const float inv = rsqrtf(var[c] + 1e-5f);
    const float sc = gam[c] * inv;
    const float sh = bet[c] - mean[c] * sc;
    const float bb = bias[c];
#pragma unroll
    for (int mf = 0; mf < 2; ++mf) {
#pragma unroll
      for (int rr = 0; rr < 4; ++rr) {
        const int m = m0 + mf * 16 + kg * 4 + rr;
        float vv = (acc[mf][nf][rr] + bb) * sc + sh;
        vv = fmaxf(vv, 0.f);
        out_t[((y * WW + x0 + m) << 6) + c] = f2bf(vv);
      }
    }
  }
}

// ---------------------------------------------------------------------------
// K3: conv2 64->32, NHWC bf16, XOR-swizzled A-tile; full pb2 staged in LDS.
// ---------------------------------------------------------------------------
__global__ __launch_bounds__(256) void conv2_mfma_kernel(
    const unsigned short* __restrict__ in_t,  // [128][256][64]
    const unsigned short* __restrict__ pb,    // [9][2][4][32][8]
    const float* __restrict__ bias, const float* __restrict__ gam,
    const float* __restrict__ bet, const float* __restrict__ mean,
    const float* __restrict__ var, unsigned short* __restrict__ out_t) {
  __shared__ unsigned short a_sh[3 * 66 * 64];  // 25344 B
  __shared__ unsigned short b_sh[18432];        // 36864 B (all of pb2)
  char* const ab = (char*)a_sh;
  const int bid = blockIdx.x;
  const int tid = threadIdx.x;
  MAP_YX4();
  const int lane = tid & 63;
  const int wv = tid >> 6;
  const int m0 = (wv >> 1) * 32;
  const int n0 = (wv & 1) * 16;
  const int col = lane & 15;
  const int kg = lane >> 4;

  f32x4 acc[2];
  acc[0] = 0.f;
  acc[1] = 0.f;

  {  // stage all weights (2304 vec8 = 9/thread)
    const bf16x8* pbv = (const bf16x8*)pb;
    bf16x8* bsl = (bf16x8*)b_sh;
#pragma unroll
    for (int it = 0; it < 9; ++it) bsl[tid + it * 256] = pbv[tid + it * 256];
  }
  for (int i = tid; i < 1584; i += 256) {  // 3*66*8
    const int r = i >> 3;
    const int q = i & 7;
    const int rowy = r / 66;
    const int xx = r % 66;
    const int gy = y + rowy - 1;
    const int gx = x0 - 1 + xx;
    bf16x8 v = {0, 0, 0, 0, 0, 0, 0, 0};
    if (gy >= 0 && gy < HH && gx >= 0 && gx < WW)
      v = *reinterpret_cast<const bf16x8*>(&in_t[((gy * WW + gx) << 6) + q * 8]);
    const int byte = ((r << 7) + (q << 4)) ^ ((r & 7) << 4);
    *reinterpret_cast<bf16x8*>(ab + byte) = v;
  }
  __syncthreads();

  const bf16x8* bsl = (const bf16x8*)b_sh;
#pragma unroll
  for (int pos = 0; pos < 9; ++pos) {
    const int ky = pos / 3;
    const int kx = pos % 3;
#pragma unroll
    for (int kc = 0; kc < 2; ++kc) {
      const bf16x8 bv = bsl[((pos * 2 + kc) * 4 + kg) * 32 + n0 + col];
#pragma unroll
      for (int mf = 0; mf < 2; ++mf) {
        const int r = ky * 66 + m0 + mf * 16 + col + kx;
        const int byte = ((r << 7) + (kc << 6) + (kg << 4)) ^ ((r & 7) << 4);
        const bf16x8 av = *reinterpret_cast<const bf16x8*>(ab + byte);
        acc[mf] = __builtin_amdgcn_mfma_f32_16x16x32_bf16(av, bv, acc[mf], 0, 0, 0);
      }
    }
  }

  const int c = n0 + col;
  const float inv = rsqrtf(var[c] + 1e-5f);
  const float sc = gam[c] * inv;
  const float sh = bet[c] - mean[c] * sc;
  const float bb = bias[c];
#pragma unroll
  for (int mf = 0; mf < 2; ++mf) {
#pragma unroll
    for (int rr = 0; rr < 4; ++rr) {
      const int m = m0 + mf * 16 + kg * 4 + rr;
      float vv = (acc[mf][rr] + bb) * sc + sh;
      vv = fmaxf(vv, 0.f);
      out_t[((y * WW + x0 + m) << 5) + c] = f2bf(vv);
    }
  }
}

// ---------------------------------------------------------------------------
// K4: conv3 32->8 (N padded to 16), NHWC bf16; pb3 staged in LDS.
// ---------------------------------------------------------------------------
__global__ __launch_bounds__(256) void conv3_mfma_kernel(
    const unsigned short* __restrict__ in_t,  // [128][256][32]
    const unsigned short* __restrict__ pb,    // [9][4][16][8]
    const float* __restrict__ bias, const float* __restrict__ gam,
    const float* __restrict__ bet, const float* __restrict__ mean,
    const float* __restrict__ var, unsigned short* __restrict__ out_t) {
  __shared__ unsigned short a_sh[3 * 66 * 32];  // 12672 B
  __shared__ unsigned short b_sh[4608];         // 9216 B (all of pb3)
  char* const ab = (char*)a_sh;
  const int bid = blockIdx.x;
  const int tid = threadIdx.x;
  MAP_YX4();
  const int lane = tid & 63;
  const int wv = tid >> 6;
  const int m0 = wv * 16;
  const int col = lane & 15;
  const int kg = lane >> 4;

  f32x4 acc = 0.f;

  {
    const bf16x8* pbv = (const bf16x8*)pb;
    bf16x8* bsl = (bf16x8*)b_sh;
    for (int s = tid; s < 576; s += 256) bsl[s] = pbv[s];
  }
  for (int i = tid; i < 792; i += 256) {  // 3*66*4
    const int r = i >> 2;
    const int q = i & 3;
    const int rowy = r / 66;
    const int xx = r % 66;
    const int gy = y + rowy - 1;
    const int gx = x0 - 1 + xx;
    bf16x8 v = {0, 0, 0, 0, 0, 0, 0, 0};
    if (gy >= 0 && gy < HH && gx >= 0 && gx < WW)
      v = *reinterpret_cast<const bf16x8*>(&in_t[((gy * WW + gx) << 5) + q * 8]);
    const int byte = ((r << 6) + (q << 4)) ^ ((r & 3) << 4);
    *reinterpret_cast<bf16x8*>(ab + byte) = v;
  }
  __syncthreads();

  const bf16x8* bsl = (const bf16x8*)b_sh;
#pragma unroll
  for (int pos = 0; pos < 9; ++pos) {
    const int ky = pos / 3;
    const int kx = pos % 3;
    const bf16x8 bv = bsl[(pos * 4 + kg) * 16 + col];
    const int r = ky * 66 + m0 + col + kx;
    const int byte = ((r << 6) + (kg << 4)) ^ ((r & 3) << 4);
    const bf16x8 av = *reinterpret_cast<const bf16x8*>(ab + byte);
    acc = __builtin_amdgcn_mfma_f32_16x16x32_bf16(av, bv, acc, 0, 0, 0);
  }

  if (col < 8) {
    const int c = col;
    const float inv = rsqrtf(var[c] + 1e-5f);
    const float sc = gam[c] * inv;
    const float sh = bet[c] - mean[c] * sc;
    const float bb = bias[c];
#pragma unroll
    for (int rr = 0; rr < 4; ++rr) {
      const int m = m0 + kg * 4 + rr;
      float vv = (acc[rr] + bb) * sc + sh;
      vv = fmaxf(vv, 0.f);
      out_t[((y * WW + x0 + m) << 3) + c] = f2bf(vv);
    }
  }
}

// ---------------------------------------------------------------------------
// K5: conv4 8->1, per-pixel direct; 128 blocks, one y-row each (XCD-mapped).
// ---------------------------------------------------------------------------
__global__ __launch_bounds__(256) void conv4_kernel(
    const unsigned short* __restrict__ in_t, const float* __restrict__ w4,
    const float* __restrict__ b4, float* __restrict__ out) {
  const int bid = blockIdx.x;
  const int y = ((bid & 7) << 4) + (bid >> 3);  // XCD k owns y in [16k,16k+16)
  const int x = threadIdx.x;

  float wr[3][3][8];
#pragma unroll
  for (int ci = 0; ci < 8; ++ci)
#pragma unroll
    for (int ky = 0; ky < 3; ++ky)
#pragma unroll
      for (int kx = 0; kx < 3; ++kx) wr[ky][kx][ci] = w4[(ci * 3 + ky) * 3 + kx];

  float acc = b4[0];
#pragma unroll
  for (int ky = 0; ky < 3; ++ky) {
    const int gy = y + ky - 1;
    if (gy < 0 || gy >= HH) continue;
#pragma unroll
    for (int kx = 0; kx < 3; ++kx) {
      const int gx = x + kx - 1;
      if (gx < 0 || gx >= WW) continue;
      const bf16x8 v =
          *reinterpret_cast<const bf16x8*>(&in_t[((gy << 8) + gx) << 3]);
#pragma unroll
      for (int ci = 0; ci < 8; ++ci) acc += bf2f(v[ci]) * wr[ky][kx][ci];
    }
  }
  out[y * WW + x] = acc;
}

// ---------------------------------------------------------------------------
extern "C" void kernel_launch(void* const* d_in, const int* in_sizes, int n_in,
                              void* d_out, int out_size, void* d_ws,
                              size_t ws_size, hipStream_t stream) {
  const float* left = (const float*)d_in[0];
  const float* right = (const float*)d_in[1];
  const float* w1 = (const float*)d_in[2];
  const float* b1 = (const float*)d_in[3];
  const float* g1 = (const float*)d_in[4];
  const float* be1 = (const float*)d_in[5];
  const float* m1 = (const float*)d_in[6];
  const float* v1 = (const float*)d_in[7];
  const float* w2 = (const float*)d_in[8];
  const float* b2 = (const float*)d_in[9];
  const float* g2 = (const float*)d_in[10];
  const float* be2 = (const float*)d_in[11];
  const float* m2 = (const float*)d_in[12];
  const float* v2 = (const float*)d_in[13];
  const float* w3 = (const float*)d_in[14];
  const float* b3 = (const float*)d_in[15];
  const float* g3 = (const float*)d_in[16];
  const float* be3 = (const float*)d_in[17];
  const float* m3 = (const float*)d_in[18];
  const float* v3 = (const float*)d_in[19];
  const float* w4 = (const float*)d_in[20];
  const float* b4 = (const float*)d_in[21];

  // Workspace:
  //  [0, 14680064)   cost_t bf16 [128][256][224]
  //  region: +0 pw1 (262144) | +262144 pb2 (65536) | +327680 pb3 (65536)
  //          +393216  o1_t bf16 [128][256][64] (4194304)
  //          +4587520 o2_t bf16 [128][256][32] (2097152)
  //          +6684672 o3_t bf16 [128][256][8]  (524288)
  char* ws = (char*)d_ws;
  unsigned short* cost_t = (unsigned short*)ws;
  char* region = ws + 14680064;
  unsigned short* pw1 = (unsigned short*)(region + 0);
  unsigned short* pb2 = (unsigned short*)(region + 262144);
  unsigned short* pb3 = (unsigned short*)(region + 327680);
  unsigned short* o1t = (unsigned short*)(region + 393216);
  unsigned short* o2t = (unsigned short*)(region + 4587520);
  unsigned short* o3t = (unsigned short*)(region + 6684672);
  float* o4 = (float*)d_out;

  k1_cv_pack<<<1106, 256, 0, stream>>>(left, right, w1, w2, w3, pw1, pb2, pb3,
                                       cost_t);
  conv1_mfma_kernel<<<512, 256, 0, stream>>>(cost_t, pw1, b1, g1, be1, m1, v1,
                                             o1t);
  conv2_mfma_kernel<<<512, 256, 0, stream>>>(o1t, pb2, b2, g2, be2, m2, v2,
                                             o2t);
  conv3_mfma_kernel<<<512, 256, 0, stream>>>(o2t, pb3, b3, g3, be3, m3, v3,
                                             o3t);
  conv4_kernel<<<128, 256, 0, stream>>>(o3t, w4, b4, o4);
}

// Round 10
// 48.884 us; speedup vs baseline: 5.6860x; 1.0083x over previous
//
#include <hip/hip_runtime.h>

#define HH 128
#define WW 256
#define CV_C 32
#define DISP 200

typedef __attribute__((ext_vector_type(4))) float f32x4;
typedef __attribute__((ext_vector_type(8))) short bf16x8;

__device__ inline unsigned short f2bf(float f) {
  unsigned int u = __float_as_uint(f);
  u = (u + 0x7FFFu + ((u >> 16) & 1u)) >> 16;  // RNE
  return (unsigned short)u;
}

__device__ inline float bf2f(short s) {
  return __uint_as_float(((unsigned int)(unsigned short)s) << 16);
}

// XCD-consistent job mapping for 512-block kernels (4 x-tiles x 128 y):
// XCD k = bid&7 owns y in [k*16, k*16+16) across ALL kernels, so each row's
// producer and consumer (and y-halo neighbors) share one XCD's L2.
#define MAP_YX4()                                   \
  const int slot = bid >> 3;                        \
  const int y = ((bid & 7) << 4) + (slot & 15);     \
  const int x0 = (slot >> 4) << 6;

// ---------------------------------------------------------------------------
// K1: blocks 0..511 cost-volume MFMA (critical path first), 512..1105 packs.
// CV: cost[d,y,x] = sum_c L[c,y,x]*R[c,y,x+d-200] -> cost_t bf16 [128][256][224]
// ---------------------------------------------------------------------------
__global__ __launch_bounds__(256) void k1_cv_pack(
    const float* __restrict__ left, const float* __restrict__ right,
    const float* __restrict__ w1, const float* __restrict__ w2,
    const float* __restrict__ w3, unsigned short* __restrict__ pw1,
    unsigned short* __restrict__ pb2, unsigned short* __restrict__ pb3,
    unsigned short* __restrict__ cost_t) {
  __shared__ unsigned short r_sh[272][40];  // 21760 B
  __shared__ unsigned short l_hi[64][40];   // 5120 B
  __shared__ unsigned short l_lo[64][40];   // 5120 B
  __shared__ unsigned short c_sh[64][224];  // 28672 B
  const int bid = blockIdx.x;
  const int tid = threadIdx.x;

  if (bid >= 512) {  // ---- weight packing ----
    const int b = bid - 512;
    if (b < 504) {  // pw1[chunk 7][pos 9][kg 4][n 64][j 8]
      const int idx = b * 256 + tid;
      const int j = idx & 7;
      const int n = (idx >> 3) & 63;
      const int kg = (idx >> 9) & 3;
      const int cp = idx >> 11;
      const int pos = cp % 9;
      const int chunk = cp / 9;
      const int ci = chunk * 32 + kg * 8 + j;
      float v = 0.f;
      if (ci < 200) v = w1[(n * 200 + ci) * 9 + pos];
      pw1[idx] = f2bf(v);
    } else if (b < 576) {  // pb2[pos 9][kc 2][kg 4][n 32][j 8]
      const int idx = (b - 504) * 256 + tid;
      const int j = idx & 7;
      const int n = (idx >> 3) & 31;
      const int kg = (idx >> 8) & 3;
      const int kc = (idx >> 10) & 1;
      const int pos = idx >> 11;
      const int ci = kc * 32 + kg * 8 + j;
      pb2[idx] = f2bf(w2[(n * 64 + ci) * 9 + pos]);
    } else {  // pb3[pos 9][kg 4][n 16(8 real)][j 8]
      const int idx = (b - 576) * 256 + tid;
      const int j = idx & 7;
      const int n = (idx >> 3) & 15;
      const int kg = (idx >> 7) & 3;
      const int pos = idx >> 9;
      const int ci = kg * 8 + j;
      float v = 0.f;
      if (n < 8) v = w3[(n * 32 + ci) * 9 + pos];
      pb3[idx] = f2bf(v);
    }
    return;
  }

  // ---- cost volume (proven body) ----
  MAP_YX4();
  const int lane = tid & 63;
  const int wv = tid >> 6;
  const int col = lane & 15;
  const int kg = lane >> 4;

  for (int c = wv; c < CV_C; c += 4) {
    const float v = left[(c * HH + y) * WW + x0 + lane];
    const unsigned short h = f2bf(v);
    l_hi[lane][c] = h;
    l_lo[lane][c] = f2bf(v - bf2f(h));
  }
  for (int c = wv; c < CV_C; c += 4) {
    for (int pq = 0; pq < 320; pq += 64) {
      const int p = pq + lane;
      if (p < 272) {
        const int xp = x0 - 208 + p;
        float v = (xp >= 0) ? right[(c * HH + y) * WW + xp] : 0.f;
        r_sh[p][c] = f2bf(v);
      }
    }
  }
  {
    bf16x8 z = {0, 0, 0, 0, 0, 0, 0, 0};
    bf16x8* cz = (bf16x8*)c_sh;
#pragma unroll
    for (int k = 0; k < 7; ++k) cz[k * 256 + tid] = z;
  }
  __syncthreads();

  const bf16x8 b_hi = *(const bf16x8*)&l_hi[16 * wv + col][kg * 8];
  const bf16x8 b_lo = *(const bf16x8*)&l_lo[16 * wv + col][kg * 8];

  for (int t = 0; t < 14; ++t) {
    const int pq = 16 * (wv - t) + 208;
    const bf16x8 a_r = *(const bf16x8*)&r_sh[pq + col][kg * 8];
    f32x4 acc = {0.f, 0.f, 0.f, 0.f};
    acc = __builtin_amdgcn_mfma_f32_16x16x32_bf16(a_r, b_hi, acc, 0, 0, 0);
    acc = __builtin_amdgcn_mfma_f32_16x16x32_bf16(a_r, b_lo, acc, 0, 0, 0);
#pragma unroll
    for (int r = 0; r < 4; ++r) {
      const int d = 200 - 16 * t + kg * 4 + r - col;
      if (d >= 0 && d < DISP) c_sh[16 * wv + col][d] = f2bf(acc[r]);
    }
  }
  __syncthreads();

#pragma unroll
  for (int k = 0; k < 7; ++k) {
    const int s = k * 256 + tid;
    const int x = s / 28;
    const int dv = s - x * 28;
    *reinterpret_cast<bf16x8*>(&cost_t[(y * WW + x0 + x) * 224 + dv * 8]) =
        *reinterpret_cast<const bf16x8*>(&c_sh[x][dv * 8]);
  }
}

// ---------------------------------------------------------------------------
// K2: conv1 implicit GEMM bf16 MFMA, register-blocked 4M x 2N per wave.
// Block = 2 output rows x 64 px x 64 co, 4 waves: wave (r,nh) = (w>>1, w&1)
// covers row y0+r, px 0..63 (4 M-tiles), co nh*32..+32 (2 N-tiles).
// Per pos: 4 A + 2 B ds_read_b128 -> 8 MFMAs (0.75 reads/MFMA vs 1.0 before;
// LDS-pipe-bound kernel, reads/CU 2016 -> 1512). A-LDS 4 rows (halo shared
// across the 2 output rows). Accumulation order per output unchanged ->
// bit-identical result.
// ---------------------------------------------------------------------------
__global__ __launch_bounds__(256) void conv1_mfma_kernel(
    const unsigned short* __restrict__ cost_t,  // [128][256][224]
    const unsigned short* __restrict__ pw,      // [7][9][4][64][8]
    const float* __restrict__ bias, const float* __restrict__ gam,
    const float* __restrict__ bet, const float* __restrict__ mean,
    const float* __restrict__ var, unsigned short* __restrict__ out_t) {
  __shared__ unsigned short a_sh[4 * 66 * 40];     // 21120 B
  __shared__ unsigned short b_sh[9 * 4 * 64 * 8];  // 36864 B (one chunk of pw)
  const int bid = blockIdx.x;
  const int tid = threadIdx.x;
  // XCD-consistent: XCD k = bid&7 owns y-pairs p in [8k, 8k+8).
  const int slot = bid >> 3;                       // [0,32)
  const int p = ((bid & 7) << 3) + (slot & 7);     // y-pair [0,64)
  const int y0 = p << 1;
  const int x0 = (slot >> 3) << 6;                 // [0,4)*64
  const int lane = tid & 63;
  const int wv = tid >> 6;
  const int r = wv >> 1;          // output row within pair
  const int n0 = (wv & 1) * 32;   // co half
  const int col = lane & 15;
  const int kg = lane >> 4;

  // staging slots: 4 rows x 66 x 4 q = 1056 vec8 slots, 5 iters/thread
  long goff[5];
  int laddr[5];
  bool gvalid[5], lvalid[5];
#pragma unroll
  for (int it = 0; it < 5; ++it) {
    const int i = tid + it * 256;
    lvalid[it] = i < 1056;
    const int row = i / 264;
    const int rem = i % 264;
    const int xx = rem >> 2;
    const int q = rem & 3;
    const int gy = y0 + row - 1;
    const int gx = x0 - 1 + xx;
    gvalid[it] = lvalid[it] && gy >= 0 && gy < HH && gx >= 0 && gx < WW;
    goff[it] = gvalid[it] ? (long)(gy * WW + gx) * 224 + q * 8 : 0;
    laddr[it] = (row * 66 + xx) * 40 + q * 8;
  }

  f32x4 acc[4][2];
#pragma unroll
  for (int i = 0; i < 4; ++i)
#pragma unroll
    for (int jx = 0; jx < 2; ++jx) acc[i][jx] = 0.f;

  const bf16x8* pwv = (const bf16x8*)pw;  // 2304 vec8 slots per chunk
  bf16x8* bsl = (bf16x8*)b_sh;
  const bf16x8 zero = {0, 0, 0, 0, 0, 0, 0, 0};
  bf16x8 stgA[5], stgB[9];

  // prologue: stage chunk 0 (A + B)
#pragma unroll
  for (int it = 0; it < 5; ++it)
    stgA[it] = gvalid[it] ? *reinterpret_cast<const bf16x8*>(&cost_t[goff[it]])
                          : zero;
#pragma unroll
  for (int it = 0; it < 9; ++it) stgB[it] = pwv[tid + it * 256];
#pragma unroll
  for (int it = 0; it < 5; ++it)
    if (lvalid[it]) *reinterpret_cast<bf16x8*>(&a_sh[laddr[it]]) = stgA[it];
#pragma unroll
  for (int it = 0; it < 9; ++it) bsl[tid + it * 256] = stgB[it];
  __syncthreads();

  for (int chunk = 0; chunk < 7; ++chunk) {
    if (chunk < 6) {  // prefetch next chunk into regs (hidden by MFMAs)
#pragma unroll
      for (int it = 0; it < 5; ++it)
        stgA[it] = gvalid[it] ? *reinterpret_cast<const bf16x8*>(
                                    &cost_t[goff[it] + (chunk + 1) * 32])
                              : zero;
      const bf16x8* pwn = pwv + (chunk + 1) * 2304;
#pragma unroll
      for (int it = 0; it < 9; ++it) stgB[it] = pwn[tid + it * 256];
    }
    const bf16x8* av = (const bf16x8*)a_sh;
#pragma unroll
    for (int pos = 0; pos < 9; ++pos) {
      const int ky = pos / 3;
      const int kx = pos % 3;
      const bf16x8 b0v = bsl[(pos * 4 + kg) * 64 + n0 + col];
      const bf16x8 b1v = bsl[(pos * 4 + kg) * 64 + n0 + 16 + col];
      bf16x8 af[4];
#pragma unroll
      for (int mt = 0; mt < 4; ++mt)
        af[mt] = av[((r + ky) * 66 + mt * 16 + col + kx) * 5 + kg];
#pragma unroll
      for (int mt = 0; mt < 4; ++mt) {
        acc[mt][0] =
            __builtin_amdgcn_mfma_f32_16x16x32_bf16(af[mt], b0v, acc[mt][0], 0, 0, 0);
        acc[mt][1] =
            __builtin_amdgcn_mfma_f32_16x16x32_bf16(af[mt], b1v, acc[mt][1], 0, 0, 0);
      }
    }
    if (chunk < 6) {
      __syncthreads();  // all waves done reading a_sh/b_sh for this chunk
#pragma unroll
      for (int it = 0; it < 5; ++it)
        if (lvalid[it]) *reinterpret_cast<bf16x8*>(&a_sh[laddr[it]]) = stgA[it];
#pragma unroll
      for (int it = 0; it < 9; ++it) bsl[tid + it * 256] = stgB[it];
      __syncthreads();  // new chunk visible
    }
  }

  // epilogue: bias + BN + ReLU -> o1_t NHWC bf16 [128][256][64]
  const int y = y0 + r;
#pragma unroll
  for (int nf = 0; nf < 2; ++nf) {
    const int c = n0 + nf * 16 + col;
    const float inv = rsqrtf(var[c] + 1e-5f);
    const float sc = gam[c] * inv;
    const float sh = bet[c] - mean[c] * sc;
    const float bb = bias[c];
#pragma unroll
    for (int mt = 0; mt < 4; ++mt) {
#pragma unroll
      for (int rr = 0; rr < 4; ++rr) {
        const int m = mt * 16 + kg * 4 + rr;
        float vv = (acc[mt][nf][rr] + bb) * sc + sh;
        vv = fmaxf(vv, 0.f);
        out_t[((y * WW + x0 + m) << 6) + c] = f2bf(vv);
      }
    }
  }
}

// ---------------------------------------------------------------------------
// K3: conv2 64->32, NHWC bf16, XOR-swizzled A-tile; full pb2 staged in LDS.
// ---------------------------------------------------------------------------
__global__ __launch_bounds__(256) void conv2_mfma_kernel(
    const unsigned short* __restrict__ in_t,  // [128][256][64]
    const unsigned short* __restrict__ pb,    // [9][2][4][32][8]
    const float* __restrict__ bias, const float* __restrict__ gam,
    const float* __restrict__ bet, const float* __restrict__ mean,
    const float* __restrict__ var, unsigned short* __restrict__ out_t) {
  __shared__ unsigned short a_sh[3 * 66 * 64];  // 25344 B
  __shared__ unsigned short b_sh[18432];        // 36864 B (all of pb2)
  char* const ab = (char*)a_sh;
  const int bid = blockIdx.x;
  const int tid = threadIdx.x;
  MAP_YX4();
  const int lane = tid & 63;
  const int wv = tid >> 6;
  const int m0 = (wv >> 1) * 32;
  const int n0 = (wv & 1) * 16;
  const int col = lane & 15;
  const int kg = lane >> 4;

  f32x4 acc[2];
  acc[0] = 0.f;
  acc[1] = 0.f;

  {  // stage all weights (2304 vec8 = 9/thread)
    const bf16x8* pbv = (const bf16x8*)pb;
    bf16x8* bsl = (bf16x8*)b_sh;
#pragma unroll
    for (int it = 0; it < 9; ++it) bsl[tid + it * 256] = pbv[tid + it * 256];
  }
  for (int i = tid; i < 1584; i += 256) {  // 3*66*8
    const int r = i >> 3;
    const int q = i & 7;
    const int rowy = r / 66;
    const int xx = r % 66;
    const int gy = y + rowy - 1;
    const int gx = x0 - 1 + xx;
    bf16x8 v = {0, 0, 0, 0, 0, 0, 0, 0};
    if (gy >= 0 && gy < HH && gx >= 0 && gx < WW)
      v = *reinterpret_cast<const bf16x8*>(&in_t[((gy * WW + gx) << 6) + q * 8]);
    const int byte = ((r << 7) + (q << 4)) ^ ((r & 7) << 4);
    *reinterpret_cast<bf16x8*>(ab + byte) = v;
  }
  __syncthreads();

  const bf16x8* bsl = (const bf16x8*)b_sh;
#pragma unroll
  for (int pos = 0; pos < 9; ++pos) {
    const int ky = pos / 3;
    const int kx = pos % 3;
#pragma unroll
    for (int kc = 0; kc < 2; ++kc) {
      const bf16x8 bv = bsl[((pos * 2 + kc) * 4 + kg) * 32 + n0 + col];
#pragma unroll
      for (int mf = 0; mf < 2; ++mf) {
        const int r = ky * 66 + m0 + mf * 16 + col + kx;
        const int byte = ((r << 7) + (kc << 6) + (kg << 4)) ^ ((r & 7) << 4);
        const bf16x8 av = *reinterpret_cast<const bf16x8*>(ab + byte);
        acc[mf] = __builtin_amdgcn_mfma_f32_16x16x32_bf16(av, bv, acc[mf], 0, 0, 0);
      }
    }
  }

  const int c = n0 + col;
  const float inv = rsqrtf(var[c] + 1e-5f);
  const float sc = gam[c] * inv;
  const float sh = bet[c] - mean[c] * sc;
  const float bb = bias[c];
#pragma unroll
  for (int mf = 0; mf < 2; ++mf) {
#pragma unroll
    for (int rr = 0; rr < 4; ++rr) {
      const int m = m0 + mf * 16 + kg * 4 + rr;
      float vv = (acc[mf][rr] + bb) * sc + sh;
      vv = fmaxf(vv, 0.f);
      out_t[((y * WW + x0 + m) << 5) + c] = f2bf(vv);
    }
  }
}

// ---------------------------------------------------------------------------
// K4: conv3 32->8 (N padded to 16), NHWC bf16; pb3 staged in LDS.
// ---------------------------------------------------------------------------
__global__ __launch_bounds__(256) void conv3_mfma_kernel(
    const unsigned short* __restrict__ in_t,  // [128][256][32]
    const unsigned short* __restrict__ pb,    // [9][4][16][8]
    const float* __restrict__ bias, const float* __restrict__ gam,
    const float* __restrict__ bet, const float* __restrict__ mean,
    const float* __restrict__ var, unsigned short* __restrict__ out_t) {
  __shared__ unsigned short a_sh[3 * 66 * 32];  // 12672 B
  __shared__ unsigned short b_sh[4608];         // 9216 B (all of pb3)
  char* const ab = (char*)a_sh;
  const int bid = blockIdx.x;
  const int tid = threadIdx.x;
  MAP_YX4();
  const int lane = tid & 63;
  const int wv = tid >> 6;
  const int m0 = wv * 16;
  const int col = lane & 15;
  const int kg = lane >> 4;

  f32x4 acc = 0.f;

  {
    const bf16x8* pbv = (const bf16x8*)pb;
    bf16x8* bsl = (bf16x8*)b_sh;
    for (int s = tid; s < 576; s += 256) bsl[s] = pbv[s];
  }
  for (int i = tid; i < 792; i += 256) {  // 3*66*4
    const int r = i >> 2;
    const int q = i & 3;
    const int rowy = r / 66;
    const int xx = r % 66;
    const int gy = y + rowy - 1;
    const int gx = x0 - 1 + xx;
    bf16x8 v = {0, 0, 0, 0, 0, 0, 0, 0};
    if (gy >= 0 && gy < HH && gx >= 0 && gx < WW)
      v = *reinterpret_cast<const bf16x8*>(&in_t[((gy * WW + gx) << 5) + q * 8]);
    const int byte = ((r << 6) + (q << 4)) ^ ((r & 3) << 4);
    *reinterpret_cast<bf16x8*>(ab + byte) = v;
  }
  __syncthreads();

  const bf16x8* bsl = (const bf16x8*)b_sh;
#pragma unroll
  for (int pos = 0; pos < 9; ++pos) {
    const int ky = pos / 3;
    const int kx = pos % 3;
    const bf16x8 bv = bsl[(pos * 4 + kg) * 16 + col];
    const int r = ky * 66 + m0 + col + kx;
    const int byte = ((r << 6) + (kg << 4)) ^ ((r & 3) << 4);
    const bf16x8 av = *reinterpret_cast<const bf16x8*>(ab + byte);
    acc = __builtin_amdgcn_mfma_f32_16x16x32_bf16(av, bv, acc, 0, 0, 0);
  }

  if (col < 8) {
    const int c = col;
    const float inv = rsqrtf(var[c] + 1e-5f);
    const float sc = gam[c] * inv;
    const float sh = bet[c] - mean[c] * sc;
    const float bb = bias[c];
#pragma unroll
    for (int rr = 0; rr < 4; ++rr) {
      const int m = m0 + kg * 4 + rr;
      float vv = (acc[rr] + bb) * sc + sh;
      vv = fmaxf(vv, 0.f);
      out_t[((y * WW + x0 + m) << 3) + c] = f2bf(vv);
    }
  }
}

// ---------------------------------------------------------------------------
// K5: conv4 8->1, per-pixel direct; 128 blocks, one y-row each (XCD-mapped).
// ---------------------------------------------------------------------------
__global__ __launch_bounds__(256) void conv4_kernel(
    const unsigned short* __restrict__ in_t, const float* __restrict__ w4,
    const float* __restrict__ b4, float* __restrict__ out) {
  const int bid = blockIdx.x;
  const int y = ((bid & 7) << 4) + (bid >> 3);  // XCD k owns y in [16k,16k+16)
  const int x = threadIdx.x;

  float wr[3][3][8];
#pragma unroll
  for (int ci = 0; ci < 8; ++ci)
#pragma unroll
    for (int ky = 0; ky < 3; ++ky)
#pragma unroll
      for (int kx = 0; kx < 3; ++kx) wr[ky][kx][ci] = w4[(ci * 3 + ky) * 3 + kx];

  float acc = b4[0];
#pragma unroll
  for (int ky = 0; ky < 3; ++ky) {
    const int gy = y + ky - 1;
    if (gy < 0 || gy >= HH) continue;
#pragma unroll
    for (int kx = 0; kx < 3; ++kx) {
      const int gx = x + kx - 1;
      if (gx < 0 || gx >= WW) continue;
      const bf16x8 v =
          *reinterpret_cast<const bf16x8*>(&in_t[((gy << 8) + gx) << 3]);
#pragma unroll
      for (int ci = 0; ci < 8; ++ci) acc += bf2f(v[ci]) * wr[ky][kx][ci];
    }
  }
  out[y * WW + x] = acc;
}

// ---------------------------------------------------------------------------
extern "C" void kernel_launch(void* const* d_in, const int* in_sizes, int n_in,
                              void* d_out, int out_size, void* d_ws,
                              size_t ws_size, hipStream_t stream) {
  const float* left = (const float*)d_in[0];
  const float* right = (const float*)d_in[1];
  const float* w1 = (const float*)d_in[2];
  const float* b1 = (const float*)d_in[3];
  const float* g1 = (const float*)d_in[4];
  const float* be1 = (const float*)d_in[5];
  const float* m1 = (const float*)d_in[6];
  const float* v1 = (const float*)d_in[7];
  const float* w2 = (const float*)d_in[8];
  const float* b2 = (const float*)d_in[9];
  const float* g2 = (const float*)d_in[10];
  const float* be2 = (const float*)d_in[11];
  const float* m2 = (const float*)d_in[12];
  const float* v2 = (const float*)d_in[13];
  const float* w3 = (const float*)d_in[14];
  const float* b3 = (const float*)d_in[15];
  const float* g3 = (const float*)d_in[16];
  const float* be3 = (const float*)d_in[17];
  const float* m3 = (const float*)d_in[18];
  const float* v3 = (const float*)d_in[19];
  const float* w4 = (const float*)d_in[20];
  const float* b4 = (const float*)d_in[21];

  // Workspace:
  //  [0, 14680064)   cost_t bf16 [128][256][224]
  //  region: +0 pw1 (262144) | +262144 pb2 (65536) | +327680 pb3 (65536)
  //          +393216  o1_t bf16 [128][256][64] (4194304)
  //          +4587520 o2_t bf16 [128][256][32] (2097152)
  //          +6684672 o3_t bf16 [128][256][8]  (524288)
  char* ws = (char*)d_ws;
  unsigned short* cost_t = (unsigned short*)ws;
  char* region = ws + 14680064;
  unsigned short* pw1 = (unsigned short*)(region + 0);
  unsigned short* pb2 = (unsigned short*)(region + 262144);
  unsigned short* pb3 = (unsigned short*)(region + 327680);
  unsigned short* o1t = (unsigned short*)(region + 393216);
  unsigned short* o2t = (unsigned short*)(region + 4587520);
  unsigned short* o3t = (unsigned short*)(region + 6684672);
  float* o4 = (float*)d_out;

  k1_cv_pack<<<1106, 256, 0, stream>>>(left, right, w1, w2, w3, pw1, pb2, pb3,
                                       cost_t);
  conv1_mfma_kernel<<<256, 256, 0, stream>>>(cost_t, pw1, b1, g1, be1, m1, v1,
                                             o1t);
  conv2_mfma_kernel<<<512, 256, 0, stream>>>(o1t, pb2, b2, g2, be2, m2, v2,
                                             o2t);
  conv3_mfma_kernel<<<512, 256, 0, stream>>>(o2t, pb3, b3, g3, be3, m3, v3,
                                             o3t);
  conv4_kernel<<<128, 256, 0, stream>>>(o3t, w4, b4, o4);
}